// Round 2
// baseline (974.261 us; speedup 1.0000x reference)
//
#include <hip/hip_runtime.h>
#include <hip/hip_bf16.h>
#include <math.h>

#define S_LEN  2048
#define HQ     16
#define HKV    2
#define GQ     8      // Hq / Hkv
#define DH     64
#define LCC    32     // compression block
#define CSTRIDE 16
#define SC     127    // (S - LC)/STRIDE + 1
#define LB     64     // selection block
#define KSEL   8
#define WIN    512
#define NB     32     // S / LB
#define NOUT   31     // pooled length before pad
#define QT     16     // queries per block in cmp kernel
#define SCALE  0.125f

// ---------------- Stage A: conv1d compression of K and V ----------------
// ck[h][c][o] = sum_{i,t} k[c*16+t][h][i] * wk[o][i][t]
__global__ __launch_bounds__(128) void nsa_conv_kernel(
    const float* __restrict__ k, const float* __restrict__ v,
    const float* __restrict__ wk, const float* __restrict__ wv,
    float* __restrict__ ck, float* __restrict__ cv) {
  int c = blockIdx.x % SC;
  int h = blockIdx.x / SC;
  __shared__ float kin[LCC * DH];
  __shared__ float vin[LCC * DH];
  int tid = threadIdx.x;
  for (int f = tid; f < LCC * DH / 4; f += 128) {
    int tt = f >> 4, i4 = f & 15;
    int row = c * CSTRIDE + tt;
    ((float4*)kin)[f] = ((const float4*)(k + ((size_t)row * HKV + h) * DH))[i4];
    ((float4*)vin)[f] = ((const float4*)(v + ((size_t)row * HKV + h) * DH))[i4];
  }
  __syncthreads();
  int o = tid & 63;
  const float* w  = (tid >= 64 ? wv : wk) + (size_t)o * (DH * LCC);
  const float* in = (tid >= 64 ? vin : kin);
  float acc = 0.f;
  for (int i = 0; i < DH; ++i)
    for (int u = 0; u < LCC; ++u)
      acc = fmaf(in[u * DH + i], w[i * LCC + u], acc);
  float* dst = (tid >= 64 ? cv : ck);
  dst[((size_t)h * SC + c) * DH + o] = acc;
}

// ---- Stage B: compressed attention + pooling + top-8 selection ----
__global__ __launch_bounds__(256) void nsa_cmp_kernel(
    const float* __restrict__ q, const float* __restrict__ wg,
    const float* __restrict__ ck, const float* __restrict__ cv,
    float* __restrict__ out, int* __restrict__ sel) {
  int h  = blockIdx.x / (S_LEN / QT);
  int s0 = (blockIdx.x % (S_LEN / QT)) * QT;
  int tid = threadIdx.x;
  __shared__ float sckT[DH * SC];     // transposed: [d][c]
  __shared__ float scv[SC * DH];      // row-major:  [c][d]
  __shared__ float qs[GQ * DH];
  __shared__ float sc[GQ][SC + 1];
  __shared__ float pkv[SC + 1];
  __shared__ float pooled[NB];
  __shared__ float gsh[GQ];

  for (int f = tid; f < SC * DH / 4; f += 256) {
    int c = f >> 4, i4 = f & 15;
    float4 kk = ((const float4*)(ck + (size_t)h * SC * DH))[f];
    float4 vv = ((const float4*)(cv + (size_t)h * SC * DH))[f];
    sckT[(i4 * 4 + 0) * SC + c] = kk.x;
    sckT[(i4 * 4 + 1) * SC + c] = kk.y;
    sckT[(i4 * 4 + 2) * SC + c] = kk.z;
    sckT[(i4 * 4 + 3) * SC + c] = kk.w;
    ((float4*)scv)[f] = vv;
  }

  for (int qq = 0; qq < QT; ++qq) {
    int s = s0 + qq;
    for (int f = tid; f < GQ * DH / 4; f += 256)
      ((float4*)qs)[f] = ((const float4*)(q + ((size_t)s * HQ + h * GQ) * DH))[f];
    __syncthreads();
    int nc = (s >= LCC - 1) ? ((s - (LCC - 1)) >> 4) + 1 : 0;  // visible compressed positions

    // scores
    for (int item = tid; item < GQ * SC; item += 256) {
      int gi = item / SC, c = item % SC;
      if (c < nc) {
        const float* qp = qs + gi * DH;
        float d = 0.f;
        for (int dd = 0; dd < DH; ++dd) d = fmaf(qp[dd], sckT[dd * SC + c], d);
        sc[gi][c] = d * SCALE;
      }
    }
    if (tid < GQ) {   // gate e=2 (cmp)
      const float* qp = qs + tid * DH;
      float d = 0.f;
      for (int dd = 0; dd < DH; ++dd) d = fmaf(qp[dd], wg[2 * DH + dd], d);
      gsh[tid] = d;
    }
    __syncthreads();

    // softmax per head (127 entries, nc visible)
    {
      int gi = tid >> 5, j = tid & 31;
      float m = -INFINITY;
      for (int c = j; c < nc; c += 32) m = fmaxf(m, sc[gi][c]);
      for (int off = 16; off; off >>= 1) m = fmaxf(m, __shfl_xor(m, off, 32));
      float ssum = 0.f;
      for (int c = j; c < nc; c += 32) {
        float p = expf(sc[gi][c] - m);
        sc[gi][c] = p; ssum += p;
      }
      for (int off = 16; off; off >>= 1) ssum += __shfl_xor(ssum, off, 32);
      float inv = 1.f / fmaxf(ssum, 1e-20f);
      for (int c = j; c < SC; c += 32) {
        if (c < nc) sc[gi][c] *= inv; else sc[gi][c] = 0.f;
      }
    }
    __syncthreads();

    // p_kv = sum over heads
    for (int c = tid; c < SC; c += 256) {
      float t = 0.f;
      for (int gi = 0; gi < GQ; ++gi) t += sc[gi][c];
      pkv[c] = t;
    }
    __syncthreads();

    // pooled (5-tap mean, stride 4), pad with -1
    if (tid < NB) {
      if (tid < NOUT) {
        float t = 0.f;
        for (int u = 0; u < 5; ++u) t += pkv[tid * 4 + u];
        pooled[tid] = t / 5.0f;
      } else pooled[tid] = -1.0f;
    }
    __syncthreads();

    // cmp_o and gated write to out
    for (int item = tid; item < GQ * DH; item += 256) {
      int gi = item >> 6, d = item & 63;
      float acc = 0.f;
      for (int c = 0; c < nc; ++c) acc = fmaf(sc[gi][c], scv[c * DH + d], acc);
      out[((size_t)s * HQ + h * GQ + gi) * DH + d] = gsh[gi] * acc;
    }

    // exact top-8 (value desc, lowest index on ties), current block forced
    if (tid == 0) {
      float vals[NB];
      for (int n = 0; n < NB; ++n) vals[n] = pooled[n];
      vals[s >> 6] = INFINITY;
      int* dst = sel + ((size_t)h * S_LEN + s) * KSEL;
      for (int kk = 0; kk < KSEL; ++kk) {
        float best = -INFINITY; int bi = 0;
        for (int n = 0; n < NB; ++n)
          if (vals[n] > best) { best = vals[n]; bi = n; }
        dst[kk] = bi;
        vals[bi] = -INFINITY;
      }
    }
    __syncthreads();
  }
}

// ---------------- Stage C: selected-block attention ----------------
__global__ __launch_bounds__(256) void nsa_sel_kernel(
    const float* __restrict__ q, const float* __restrict__ k,
    const float* __restrict__ v, const float* __restrict__ wg,
    const int* __restrict__ sel, float* __restrict__ out) {
  int h = blockIdx.x / S_LEN;
  int s = blockIdx.x % S_LEN;
  int tid = threadIdx.x;
  __shared__ float qs[GQ * DH];
  __shared__ float tile[LB * DH];      // K: transposed [d][r]; V: row-major [r][d]
  __shared__ float sc[GQ][KSEL * LB];
  __shared__ float gsh[GQ];
  __shared__ int sidx[KSEL];

  for (int f = tid; f < GQ * DH / 4; f += 256)
    ((float4*)qs)[f] = ((const float4*)(q + ((size_t)s * HQ + h * GQ) * DH))[f];
  if (tid < KSEL) sidx[tid] = sel[((size_t)h * S_LEN + s) * KSEL + tid];
  if (tid >= 64 && tid < 64 + GQ) {    // gate e=0 (sel)
    int gi = tid - 64;
    const float* qp = q + ((size_t)s * HQ + h * GQ + gi) * DH;
    float d = 0.f;
    for (int dd = 0; dd < DH; ++dd) d = fmaf(qp[dd], wg[0 * DH + dd], d);
    gsh[gi] = d;
  }
  __syncthreads();

  // scores
  for (int jb = 0; jb < KSEL; ++jb) {
    int base = sidx[jb] * LB;
    for (int f = tid; f < LB * DH / 4; f += 256) {
      int r = f >> 4, i4 = f & 15;
      float4 kk = ((const float4*)(k + ((size_t)(base + r) * HKV + h) * DH))[i4];
      tile[(i4 * 4 + 0) * LB + r] = kk.x;
      tile[(i4 * 4 + 1) * LB + r] = kk.y;
      tile[(i4 * 4 + 2) * LB + r] = kk.z;
      tile[(i4 * 4 + 3) * LB + r] = kk.w;
    }
    __syncthreads();
    for (int item = tid; item < GQ * LB; item += 256) {
      int gi = item >> 6, r = item & 63;
      int pos = base + r;
      float val = -INFINITY;
      if (pos <= s) {
        const float* qp = qs + gi * DH;
        float d = 0.f;
        for (int dd = 0; dd < DH; ++dd) d = fmaf(qp[dd], tile[dd * LB + r], d);
        val = d * SCALE;
      }
      sc[gi][jb * LB + r] = val;
    }
    __syncthreads();
  }

  // softmax over 512
  {
    int gi = tid >> 5, j = tid & 31;
    float m = -INFINITY;
    for (int c = j; c < KSEL * LB; c += 32) m = fmaxf(m, sc[gi][c]);
    for (int off = 16; off; off >>= 1) m = fmaxf(m, __shfl_xor(m, off, 32));
    float ssum = 0.f;
    for (int c = j; c < KSEL * LB; c += 32) {
      float p = expf(sc[gi][c] - m);
      sc[gi][c] = p; ssum += p;
    }
    for (int off = 16; off; off >>= 1) ssum += __shfl_xor(ssum, off, 32);
    float inv = 1.f / fmaxf(ssum, 1e-20f);
    for (int c = j; c < KSEL * LB; c += 32) sc[gi][c] *= inv;
  }
  __syncthreads();

  // PV: each thread owns (gi_a,d) and (gi_a+4,d)
  float acc0 = 0.f, acc1 = 0.f;
  int gi_a = tid >> 6, d_a = tid & 63;
  int gi_b = gi_a + 4;
  for (int jb = 0; jb < KSEL; ++jb) {
    int base = sidx[jb] * LB;
    for (int f = tid; f < LB * DH / 4; f += 256) {
      int r = f >> 4, i4 = f & 15;
      ((float4*)tile)[f] = ((const float4*)(v + ((size_t)(base + r) * HKV + h) * DH))[i4];
    }
    __syncthreads();
    for (int r = 0; r < LB; ++r) {
      float vv = tile[r * DH + d_a];
      acc0 = fmaf(sc[gi_a][jb * LB + r], vv, acc0);
      acc1 = fmaf(sc[gi_b][jb * LB + r], vv, acc1);
    }
    __syncthreads();
  }
  out[((size_t)s * HQ + h * GQ + gi_a) * DH + d_a] += gsh[gi_a] * acc0;
  out[((size_t)s * HQ + h * GQ + gi_b) * DH + d_a] += gsh[gi_b] * acc1;
}

// ---------------- Stage D: sliding-window attention ----------------
__global__ __launch_bounds__(256) void nsa_swa_kernel(
    const float* __restrict__ q, const float* __restrict__ k,
    const float* __restrict__ v, const float* __restrict__ wg,
    float* __restrict__ out) {
  int h = blockIdx.x / S_LEN;
  int s = blockIdx.x % S_LEN;
  int tid = threadIdx.x;
  int t0 = (s >= WIN) ? s - (WIN - 1) : 0;
  int L  = s - t0 + 1;
  int ntiles = (L + LB - 1) / LB;
  __shared__ float qs[GQ * DH];
  __shared__ float tile[LB * DH];
  __shared__ float sc[GQ][WIN];
  __shared__ float gsh[GQ];

  for (int i = tid; i < GQ * WIN; i += 256) ((float*)sc)[i] = -INFINITY;
  for (int f = tid; f < GQ * DH / 4; f += 256)
    ((float4*)qs)[f] = ((const float4*)(q + ((size_t)s * HQ + h * GQ) * DH))[f];
  if (tid >= 64 && tid < 64 + GQ) {   // gate e=1 (swa)
    int gi = tid - 64;
    const float* qp = q + ((size_t)s * HQ + h * GQ + gi) * DH;
    float d = 0.f;
    for (int dd = 0; dd < DH; ++dd) d = fmaf(qp[dd], wg[1 * DH + dd], d);
    gsh[gi] = d;
  }
  __syncthreads();

  for (int jb = 0; jb < ntiles; ++jb) {
    int base = t0 + jb * LB;
    for (int f = tid; f < LB * DH / 4; f += 256) {
      int r = f >> 4, i4 = f & 15;
      float4 kk = ((const float4*)(k + ((size_t)(base + r) * HKV + h) * DH))[i4];
      tile[(i4 * 4 + 0) * LB + r] = kk.x;
      tile[(i4 * 4 + 1) * LB + r] = kk.y;
      tile[(i4 * 4 + 2) * LB + r] = kk.z;
      tile[(i4 * 4 + 3) * LB + r] = kk.w;
    }
    __syncthreads();
    for (int item = tid; item < GQ * LB; item += 256) {
      int gi = item >> 6, r = item & 63;
      int pos = base + r;
      if (pos <= s) {
        const float* qp = qs + gi * DH;
        float d = 0.f;
        for (int dd = 0; dd < DH; ++dd) d = fmaf(qp[dd], tile[dd * LB + r], d);
        sc[gi][jb * LB + r] = d * SCALE;
      }
    }
    __syncthreads();
  }

  {
    int gi = tid >> 5, j = tid & 31;
    float m = -INFINITY;
    for (int c = j; c < WIN; c += 32) m = fmaxf(m, sc[gi][c]);
    for (int off = 16; off; off >>= 1) m = fmaxf(m, __shfl_xor(m, off, 32));
    float ssum = 0.f;
    for (int c = j; c < WIN; c += 32) {
      float p = expf(sc[gi][c] - m);
      sc[gi][c] = p; ssum += p;
    }
    for (int off = 16; off; off >>= 1) ssum += __shfl_xor(ssum, off, 32);
    float inv = 1.f / fmaxf(ssum, 1e-20f);
    for (int c = j; c < WIN; c += 32) sc[gi][c] *= inv;
  }
  __syncthreads();

  float acc0 = 0.f, acc1 = 0.f;
  int gi_a = tid >> 6, d_a = tid & 63;
  int gi_b = gi_a + 4;
  for (int jb = 0; jb < ntiles; ++jb) {
    int base = t0 + jb * LB;
    for (int f = tid; f < LB * DH / 4; f += 256) {
      int r = f >> 4, i4 = f & 15;
      ((float4*)tile)[f] = ((const float4*)(v + ((size_t)(base + r) * HKV + h) * DH))[i4];
    }
    __syncthreads();
    for (int r = 0; r < LB; ++r) {
      float vv = tile[r * DH + d_a];
      acc0 = fmaf(sc[gi_a][jb * LB + r], vv, acc0);
      acc1 = fmaf(sc[gi_b][jb * LB + r], vv, acc1);
    }
    __syncthreads();
  }
  out[((size_t)s * HQ + h * GQ + gi_a) * DH + d_a] += gsh[gi_a] * acc0;
  out[((size_t)s * HQ + h * GQ + gi_b) * DH + d_a] += gsh[gi_b] * acc1;
}

extern "C" void kernel_launch(void* const* d_in, const int* in_sizes, int n_in,
                              void* d_out, int out_size, void* d_ws, size_t ws_size,
                              hipStream_t stream) {
  const float* q  = (const float*)d_in[0];
  const float* k  = (const float*)d_in[1];
  const float* v  = (const float*)d_in[2];
  const float* wk = (const float*)d_in[3];
  const float* wv = (const float*)d_in[4];
  const float* wg = (const float*)d_in[5];
  float* out = (float*)d_out;

  float* ck = (float*)d_ws;
  float* cv = ck + (size_t)HKV * SC * DH;
  int* sel  = (int*)(cv + (size_t)HKV * SC * DH);

  nsa_conv_kernel<<<HKV * SC, 128, 0, stream>>>(k, v, wk, wv, ck, cv);
  nsa_cmp_kernel<<<HKV * (S_LEN / QT), 256, 0, stream>>>(q, wg, ck, cv, out, sel);
  nsa_sel_kernel<<<HKV * S_LEN, 256, 0, stream>>>(q, k, v, wg, sel, out);
  nsa_swa_kernel<<<HKV * S_LEN, 256, 0, stream>>>(q, k, v, wg, out);
}

// Round 3
// 474.993 us; speedup vs baseline: 2.0511x; 2.0511x over previous
//
#include <hip/hip_runtime.h>
#include <hip/hip_bf16.h>
#include <math.h>

#define S_LEN  2048
#define HQ     16
#define HKV    2
#define GQ     8      // Hq / Hkv
#define DH     64
#define LCC    32     // compression block
#define CSTRIDE 16
#define SC     127    // (S - LC)/STRIDE + 1
#define LB     64     // selection block
#define KSEL   8
#define WIN    512
#define NB     32     // S / LB
#define NOUT   31     // pooled length before pad
#define QT     8      // queries per block in cmp kernel
#define SCALE  0.125f
#define SCP    (KSEL * LB + 4)   // padded score row (sel/swa): head-stride hits distinct banks
#define SCP2   132               // padded score row (cmp)

// ---------------- Stage A: conv1d compression of K and V ----------------
__global__ __launch_bounds__(128) void nsa_conv_kernel(
    const float* __restrict__ k, const float* __restrict__ v,
    const float* __restrict__ wk, const float* __restrict__ wv,
    float* __restrict__ ck, float* __restrict__ cv) {
  int c = blockIdx.x % SC;
  int h = blockIdx.x / SC;
  __shared__ float kin[LCC * DH];
  __shared__ float vin[LCC * DH];
  int tid = threadIdx.x;
  for (int f = tid; f < LCC * DH / 4; f += 128) {
    int tt = f >> 4, i4 = f & 15;
    int row = c * CSTRIDE + tt;
    ((float4*)kin)[f] = ((const float4*)(k + ((size_t)row * HKV + h) * DH))[i4];
    ((float4*)vin)[f] = ((const float4*)(v + ((size_t)row * HKV + h) * DH))[i4];
  }
  __syncthreads();
  int o = tid & 63;
  const float* w  = (tid >= 64 ? wv : wk) + (size_t)o * (DH * LCC);
  const float* in = (tid >= 64 ? vin : kin);
  float acc = 0.f;
  for (int i = 0; i < DH; ++i)
    for (int u = 0; u < LCC; ++u)
      acc = fmaf(in[u * DH + i], w[i * LCC + u], acc);
  float* dst = (tid >= 64 ? cv : ck);
  dst[((size_t)h * SC + c) * DH + o] = acc;
}

// ---- Stage B: compressed attention + pooling + top-8 selection ----
__global__ __launch_bounds__(256) void nsa_cmp_kernel(
    const float* __restrict__ q, const float* __restrict__ wg,
    const float* __restrict__ ck, const float* __restrict__ cv,
    float* __restrict__ out, int* __restrict__ sel) {
  int h  = blockIdx.x / (S_LEN / QT);
  int s0 = (blockIdx.x % (S_LEN / QT)) * QT;
  int tid = threadIdx.x;
  __shared__ float sck[SC * DH];      // K rows, float4-swizzled
  __shared__ float scv[SC * DH];      // V rows, plain
  __shared__ float qs[GQ * DH];
  __shared__ float sc[GQ][SCP2];
  __shared__ float pkv[SC + 1];
  __shared__ float gsh[GQ];
  __shared__ float red[GQ * DH];

  float4* sck4 = (float4*)sck;
  float4* scv4 = (float4*)scv;
  const float4* qs4 = (const float4*)qs;

  for (int f = tid; f < SC * 16; f += 256) {
    int c = f >> 4, c4 = f & 15;
    float4 kk = ((const float4*)(ck + (size_t)h * SC * DH))[f];
    float4 vv = ((const float4*)(cv + (size_t)h * SC * DH))[f];
    sck4[(c << 4) | (c4 ^ (c & 7))] = kk;
    scv4[f] = vv;
  }

  int d4 = tid & 15, gi2 = (tid >> 4) & 7, half = tid >> 7;

  for (int qq = 0; qq < QT; ++qq) {
    int s = s0 + qq;
    for (int f = tid; f < GQ * DH / 4; f += 256)
      ((float4*)qs)[f] = ((const float4*)(q + ((size_t)s * HQ + h * GQ) * DH))[f];
    __syncthreads();
    if (tid < GQ) {   // gate e=2 (cmp)
      float d = 0.f;
      for (int dd = 0; dd < DH; ++dd) d = fmaf(qs[tid * DH + dd], wg[2 * DH + dd], d);
      gsh[tid] = d;
    }
    int nc = (s >= LCC - 1) ? ((s - (LCC - 1)) >> 4) + 1 : 0;

    // scores: thread owns column c for 4 heads
    {
      int c = tid & 127, hg = tid >> 7;
      if (c < SC) {
        float d0 = 0.f, d1 = 0.f, d2 = 0.f, d3 = 0.f;
        if (c < nc) {
          const float4* q0 = qs4 + (hg * 4 + 0) * 16;
          const float4* q1 = qs4 + (hg * 4 + 1) * 16;
          const float4* q2 = qs4 + (hg * 4 + 2) * 16;
          const float4* q3 = qs4 + (hg * 4 + 3) * 16;
          #pragma unroll
          for (int cc = 0; cc < 16; ++cc) {
            float4 kk = sck4[(c << 4) | (cc ^ (c & 7))];
            float4 a = q0[cc], b = q1[cc], e = q2[cc], ff = q3[cc];
            d0 = fmaf(kk.x, a.x, d0); d0 = fmaf(kk.y, a.y, d0); d0 = fmaf(kk.z, a.z, d0); d0 = fmaf(kk.w, a.w, d0);
            d1 = fmaf(kk.x, b.x, d1); d1 = fmaf(kk.y, b.y, d1); d1 = fmaf(kk.z, b.z, d1); d1 = fmaf(kk.w, b.w, d1);
            d2 = fmaf(kk.x, e.x, d2); d2 = fmaf(kk.y, e.y, d2); d2 = fmaf(kk.z, e.z, d2); d2 = fmaf(kk.w, e.w, d2);
            d3 = fmaf(kk.x, ff.x, d3); d3 = fmaf(kk.y, ff.y, d3); d3 = fmaf(kk.z, ff.z, d3); d3 = fmaf(kk.w, ff.w, d3);
          }
        }
        float m0 = (c < nc) ? SCALE : 0.f;
        float ninf = (c < nc) ? 0.f : -INFINITY;
        sc[hg * 4 + 0][c] = d0 * m0 + ninf;
        sc[hg * 4 + 1][c] = d1 * m0 + ninf;
        sc[hg * 4 + 2][c] = d2 * m0 + ninf;
        sc[hg * 4 + 3][c] = d3 * m0 + ninf;
      }
    }
    __syncthreads();

    // softmax per head over SC entries (invisible = -inf -> 0)
    {
      int gi = tid >> 5, j = tid & 31;
      float m = -INFINITY;
      for (int c = j; c < SC; c += 32) m = fmaxf(m, sc[gi][c]);
      for (int off = 16; off; off >>= 1) m = fmaxf(m, __shfl_xor(m, off, 32));
      m = fmaxf(m, -1e30f);   // all-masked row (s < 31) -> p = 0, no NaN
      float ssum = 0.f;
      for (int c = j; c < SC; c += 32) {
        float p = expf(sc[gi][c] - m);
        sc[gi][c] = p; ssum += p;
      }
      for (int off = 16; off; off >>= 1) ssum += __shfl_xor(ssum, off, 32);
      float inv = 1.f / fmaxf(ssum, 1e-20f);
      for (int c = j; c < SC; c += 32) sc[gi][c] *= inv;
    }
    __syncthreads();

    // p_kv = sum over group heads
    if (tid < SC) {
      float t = 0.f;
      for (int gi = 0; gi < GQ; ++gi) t += sc[gi][tid];
      pkv[tid] = t;
    }
    __syncthreads();

    // pooled + exact top-8 (value desc, lowest index) in one wave
    if (tid < 32) {
      float pv;
      if (tid < NOUT) {
        float t = 0.f;
        #pragma unroll
        for (int u = 0; u < 5; ++u) t += pkv[tid * 4 + u];
        pv = t * 0.2f;
      } else pv = -1.0f;
      if (tid == (s >> 6)) pv = INFINITY;
      int* dst = sel + ((size_t)h * S_LEN + s) * KSEL;
      #pragma unroll
      for (int kk = 0; kk < KSEL; ++kk) {
        float v0 = pv; int i0 = tid;
        #pragma unroll
        for (int off = 16; off; off >>= 1) {
          float v1 = __shfl_xor(v0, off, 32);
          int   i1 = __shfl_xor(i0, off, 32);
          if (v1 > v0 || (v1 == v0 && i1 < i0)) { v0 = v1; i0 = i1; }
        }
        if (tid == 0) dst[kk] = i0;
        if (tid == i0) pv = -INFINITY;
      }
    }

    // PV: thread owns (head gi2, 4-wide d-slice d4, half of columns)
    {
      float4 acc = {0.f, 0.f, 0.f, 0.f};
      for (int c = half; c < nc; c += 2) {
        float p = sc[gi2][c];
        float4 vv = scv4[(c << 4) | d4];
        acc.x = fmaf(p, vv.x, acc.x);
        acc.y = fmaf(p, vv.y, acc.y);
        acc.z = fmaf(p, vv.z, acc.z);
        acc.w = fmaf(p, vv.w, acc.w);
      }
      if (half == 1) ((float4*)red)[gi2 * 16 + d4] = acc;
      __syncthreads();
      if (half == 0) {
        float4 o = ((float4*)red)[gi2 * 16 + d4];
        acc.x += o.x; acc.y += o.y; acc.z += o.z; acc.w += o.w;
        float g = gsh[gi2];
        float4* op = (float4*)(out + ((size_t)s * HQ + h * GQ + gi2) * DH) + d4;
        float4 ov;
        ov.x = g * acc.x; ov.y = g * acc.y; ov.z = g * acc.z; ov.w = g * acc.w;
        *op = ov;
      }
    }
    __syncthreads();
  }
}

// ---------------- Stage C: selected-block attention ----------------
__global__ __launch_bounds__(256) void nsa_sel_kernel(
    const float* __restrict__ q, const float* __restrict__ k,
    const float* __restrict__ v, const float* __restrict__ wg,
    const int* __restrict__ sel, float* __restrict__ out) {
  int h = blockIdx.x / S_LEN;
  int s = blockIdx.x % S_LEN;
  int tid = threadIdx.x;
  __shared__ float tile[LB * DH];
  __shared__ float sc[GQ][SCP];
  __shared__ float qs[GQ * DH];
  __shared__ float gsh[GQ];
  __shared__ float red[GQ * DH];
  __shared__ int sidx[KSEL];

  float4* tile4 = (float4*)tile;
  const float4* qs4 = (const float4*)qs;

  for (int f = tid; f < GQ * DH / 4; f += 256)
    ((float4*)qs)[f] = ((const float4*)(q + ((size_t)s * HQ + h * GQ) * DH))[f];
  if (tid < KSEL) sidx[tid] = sel[((size_t)h * S_LEN + s) * KSEL + tid];
  __syncthreads();
  if (tid < GQ) {    // gate e=0 (sel)
    float d = 0.f;
    for (int dd = 0; dd < DH; ++dd) d = fmaf(qs[tid * DH + dd], wg[0 * DH + dd], d);
    gsh[tid] = d;
  }

  // ---- scores: thread owns row r for 2 heads ----
  {
    int r = tid & 63, hp = tid >> 6;
    const float4* q0 = qs4 + (2 * hp) * 16;
    const float4* q1 = qs4 + (2 * hp + 1) * 16;
    for (int jb = 0; jb < KSEL; ++jb) {
      int base = sidx[jb] * LB;
      for (int f = tid; f < LB * 16; f += 256) {
        int rr = f >> 4, c = f & 15;
        tile4[(rr << 4) | (c ^ (rr & 7))] =
            ((const float4*)(k + ((size_t)(base + rr) * HKV + h) * DH))[c];
      }
      __syncthreads();
      float d0 = 0.f, d1 = 0.f;
      #pragma unroll
      for (int c = 0; c < 16; ++c) {
        float4 kk = tile4[(r << 4) | (c ^ (r & 7))];
        float4 a = q0[c], b = q1[c];
        d0 = fmaf(kk.x, a.x, d0); d0 = fmaf(kk.y, a.y, d0); d0 = fmaf(kk.z, a.z, d0); d0 = fmaf(kk.w, a.w, d0);
        d1 = fmaf(kk.x, b.x, d1); d1 = fmaf(kk.y, b.y, d1); d1 = fmaf(kk.z, b.z, d1); d1 = fmaf(kk.w, b.w, d1);
      }
      int pos = base + r;
      float m0 = (pos <= s) ? SCALE : 0.f;
      float ninf = (pos <= s) ? 0.f : -INFINITY;
      sc[2 * hp][jb * LB + r]     = d0 * m0 + ninf;
      sc[2 * hp + 1][jb * LB + r] = d1 * m0 + ninf;
      __syncthreads();
    }
  }

  // ---- softmax over 512 ----
  {
    int gi = tid >> 5, j = tid & 31;
    float m = -INFINITY;
    for (int c = j; c < KSEL * LB; c += 32) m = fmaxf(m, sc[gi][c]);
    for (int off = 16; off; off >>= 1) m = fmaxf(m, __shfl_xor(m, off, 32));
    float ssum = 0.f;
    for (int c = j; c < KSEL * LB; c += 32) {
      float p = expf(sc[gi][c] - m);
      sc[gi][c] = p; ssum += p;
    }
    for (int off = 16; off; off >>= 1) ssum += __shfl_xor(ssum, off, 32);
    float inv = 1.f / fmaxf(ssum, 1e-20f);
    for (int c = j; c < KSEL * LB; c += 32) sc[gi][c] *= inv;
  }
  __syncthreads();

  // ---- PV: thread owns (head gi2, d-slice d4, half of rows) ----
  {
    int d4 = tid & 15, gi2 = (tid >> 4) & 7, half = tid >> 7;
    float4 acc = {0.f, 0.f, 0.f, 0.f};
    for (int jb = 0; jb < KSEL; ++jb) {
      int base = sidx[jb] * LB;
      for (int f = tid; f < LB * 16; f += 256)
        tile4[f] = ((const float4*)(v + ((size_t)(base + (f >> 4)) * HKV + h) * DH))[f & 15];
      __syncthreads();
      int rbeg = half * 32;
      #pragma unroll 4
      for (int rr = 0; rr < 32; ++rr) {
        int rrow = rbeg + rr;
        float p = sc[gi2][jb * LB + rrow];
        float4 vv = tile4[(rrow << 4) | d4];
        acc.x = fmaf(p, vv.x, acc.x);
        acc.y = fmaf(p, vv.y, acc.y);
        acc.z = fmaf(p, vv.z, acc.z);
        acc.w = fmaf(p, vv.w, acc.w);
      }
      __syncthreads();
    }
    if (half == 1) ((float4*)red)[gi2 * 16 + d4] = acc;
    __syncthreads();
    if (half == 0) {
      float4 o = ((float4*)red)[gi2 * 16 + d4];
      acc.x += o.x; acc.y += o.y; acc.z += o.z; acc.w += o.w;
      float g = gsh[gi2];
      float4* op = (float4*)(out + ((size_t)s * HQ + h * GQ + gi2) * DH) + d4;
      float4 prev = *op;
      prev.x = fmaf(g, acc.x, prev.x);
      prev.y = fmaf(g, acc.y, prev.y);
      prev.z = fmaf(g, acc.z, prev.z);
      prev.w = fmaf(g, acc.w, prev.w);
      *op = prev;
    }
  }
}

// ---------------- Stage D: sliding-window attention ----------------
__global__ __launch_bounds__(256) void nsa_swa_kernel(
    const float* __restrict__ q, const float* __restrict__ k,
    const float* __restrict__ v, const float* __restrict__ wg,
    float* __restrict__ out) {
  int h = blockIdx.x / S_LEN;
  int s = blockIdx.x % S_LEN;
  int tid = threadIdx.x;
  int t0 = (s >= WIN) ? s - (WIN - 1) : 0;
  int nt = (s - t0 + LB) / LB;   // ceil((s-t0+1)/64), 1..8
  __shared__ float tile[LB * DH];
  __shared__ float sc[GQ][SCP];
  __shared__ float qs[GQ * DH];
  __shared__ float gsh[GQ];
  __shared__ float red[GQ * DH];

  float4* tile4 = (float4*)tile;
  const float4* qs4 = (const float4*)qs;

  for (int f = tid; f < GQ * DH / 4; f += 256)
    ((float4*)qs)[f] = ((const float4*)(q + ((size_t)s * HQ + h * GQ) * DH))[f];
  __syncthreads();
  if (tid < GQ) {    // gate e=1 (swa)
    float d = 0.f;
    for (int dd = 0; dd < DH; ++dd) d = fmaf(qs[tid * DH + dd], wg[1 * DH + dd], d);
    gsh[tid] = d;
  }

  {
    int r = tid & 63, hp = tid >> 6;
    const float4* q0 = qs4 + (2 * hp) * 16;
    const float4* q1 = qs4 + (2 * hp + 1) * 16;
    for (int jb = 0; jb < nt; ++jb) {
      int base = t0 + jb * LB;
      for (int f = tid; f < LB * 16; f += 256) {
        int rr = f >> 4, c = f & 15;
        tile4[(rr << 4) | (c ^ (rr & 7))] =
            ((const float4*)(k + ((size_t)(base + rr) * HKV + h) * DH))[c];
      }
      __syncthreads();
      float d0 = 0.f, d1 = 0.f;
      #pragma unroll
      for (int c = 0; c < 16; ++c) {
        float4 kk = tile4[(r << 4) | (c ^ (r & 7))];
        float4 a = q0[c], b = q1[c];
        d0 = fmaf(kk.x, a.x, d0); d0 = fmaf(kk.y, a.y, d0); d0 = fmaf(kk.z, a.z, d0); d0 = fmaf(kk.w, a.w, d0);
        d1 = fmaf(kk.x, b.x, d1); d1 = fmaf(kk.y, b.y, d1); d1 = fmaf(kk.z, b.z, d1); d1 = fmaf(kk.w, b.w, d1);
      }
      int pos = base + r;
      float m0 = (pos <= s) ? SCALE : 0.f;
      float ninf = (pos <= s) ? 0.f : -INFINITY;
      sc[2 * hp][jb * LB + r]     = d0 * m0 + ninf;
      sc[2 * hp + 1][jb * LB + r] = d1 * m0 + ninf;
      __syncthreads();
    }
  }

  {
    int gi = tid >> 5, j = tid & 31;
    int ncc = nt * LB;
    float m = -INFINITY;
    for (int c = j; c < ncc; c += 32) m = fmaxf(m, sc[gi][c]);
    for (int off = 16; off; off >>= 1) m = fmaxf(m, __shfl_xor(m, off, 32));
    float ssum = 0.f;
    for (int c = j; c < ncc; c += 32) {
      float p = expf(sc[gi][c] - m);
      sc[gi][c] = p; ssum += p;
    }
    for (int off = 16; off; off >>= 1) ssum += __shfl_xor(ssum, off, 32);
    float inv = 1.f / fmaxf(ssum, 1e-20f);
    for (int c = j; c < ncc; c += 32) sc[gi][c] *= inv;
  }
  __syncthreads();

  {
    int d4 = tid & 15, gi2 = (tid >> 4) & 7, half = tid >> 7;
    float4 acc = {0.f, 0.f, 0.f, 0.f};
    for (int jb = 0; jb < nt; ++jb) {
      int base = t0 + jb * LB;
      for (int f = tid; f < LB * 16; f += 256)
        tile4[f] = ((const float4*)(v + ((size_t)(base + (f >> 4)) * HKV + h) * DH))[f & 15];
      __syncthreads();
      int rbeg = half * 32;
      #pragma unroll 4
      for (int rr = 0; rr < 32; ++rr) {
        int rrow = rbeg + rr;
        float p = sc[gi2][jb * LB + rrow];
        float4 vv = tile4[(rrow << 4) | d4];
        acc.x = fmaf(p, vv.x, acc.x);
        acc.y = fmaf(p, vv.y, acc.y);
        acc.z = fmaf(p, vv.z, acc.z);
        acc.w = fmaf(p, vv.w, acc.w);
      }
      __syncthreads();
    }
    if (half == 1) ((float4*)red)[gi2 * 16 + d4] = acc;
    __syncthreads();
    if (half == 0) {
      float4 o = ((float4*)red)[gi2 * 16 + d4];
      acc.x += o.x; acc.y += o.y; acc.z += o.z; acc.w += o.w;
      float g = gsh[gi2];
      float4* op = (float4*)(out + ((size_t)s * HQ + h * GQ + gi2) * DH) + d4;
      float4 prev = *op;
      prev.x = fmaf(g, acc.x, prev.x);
      prev.y = fmaf(g, acc.y, prev.y);
      prev.z = fmaf(g, acc.z, prev.z);
      prev.w = fmaf(g, acc.w, prev.w);
      *op = prev;
    }
  }
}

extern "C" void kernel_launch(void* const* d_in, const int* in_sizes, int n_in,
                              void* d_out, int out_size, void* d_ws, size_t ws_size,
                              hipStream_t stream) {
  const float* q  = (const float*)d_in[0];
  const float* k  = (const float*)d_in[1];
  const float* v  = (const float*)d_in[2];
  const float* wk = (const float*)d_in[3];
  const float* wv = (const float*)d_in[4];
  const float* wg = (const float*)d_in[5];
  float* out = (float*)d_out;

  float* ck = (float*)d_ws;
  float* cv = ck + (size_t)HKV * SC * DH;
  int* sel  = (int*)(cv + (size_t)HKV * SC * DH);

  nsa_conv_kernel<<<HKV * SC, 128, 0, stream>>>(k, v, wk, wv, ck, cv);
  nsa_cmp_kernel<<<HKV * (S_LEN / QT), 256, 0, stream>>>(q, wg, ck, cv, out, sel);
  nsa_sel_kernel<<<HKV * S_LEN, 256, 0, stream>>>(q, k, v, wg, sel, out);
  nsa_swa_kernel<<<HKV * S_LEN, 256, 0, stream>>>(q, k, v, wg, out);
}

// Round 5
// 274.093 us; speedup vs baseline: 3.5545x; 1.7330x over previous
//
#include <hip/hip_runtime.h>
#include <hip/hip_bf16.h>
#include <math.h>

#define S_LEN  2048
#define HQ     16
#define HKV    2
#define GQ     8      // Hq / Hkv
#define DH     64
#define LCC    32     // compression block
#define CSTRIDE 16
#define SC     127    // (S - LC)/STRIDE + 1
#define LB     64     // selection block
#define KSEL   8
#define WIN    512
#define NB     32     // S / LB
#define NOUT   31     // pooled length before pad
#define QT     8      // queries per block in cmp kernel
#define QTS    8      // queries per block in selswa kernel
#define SCALE  0.125f
#define SCP2   132    // padded score row (cmp)

typedef __attribute__((ext_vector_type(8))) short bf16x8;
typedef __attribute__((ext_vector_type(4))) float f32x4;
typedef unsigned short u16;
typedef unsigned int   u32;

__device__ __forceinline__ u16 f2bf(float f) {
  u32 u = __float_as_uint(f);
  return (u16)((u + 0x7FFFu + ((u >> 16) & 1u)) >> 16);
}

// ---------------- Stage A: conv1d compression of K and V ----------------
__global__ __launch_bounds__(128) void nsa_conv_kernel(
    const float* __restrict__ k, const float* __restrict__ v,
    const float* __restrict__ wk, const float* __restrict__ wv,
    float* __restrict__ ck, float* __restrict__ cv) {
  int c = blockIdx.x % SC;
  int h = blockIdx.x / SC;
  __shared__ float kin[LCC * DH];
  __shared__ float vin[LCC * DH];
  int tid = threadIdx.x;
  for (int f = tid; f < LCC * DH / 4; f += 128) {
    int tt = f >> 4, i4 = f & 15;
    int row = c * CSTRIDE + tt;
    ((float4*)kin)[f] = ((const float4*)(k + ((size_t)row * HKV + h) * DH))[i4];
    ((float4*)vin)[f] = ((const float4*)(v + ((size_t)row * HKV + h) * DH))[i4];
  }
  __syncthreads();
  int o = tid & 63;
  const float* w  = (tid >= 64 ? wv : wk) + (size_t)o * (DH * LCC);
  const float* in = (tid >= 64 ? vin : kin);
  float acc = 0.f;
  for (int i = 0; i < DH; ++i)
    for (int u = 0; u < LCC; ++u)
      acc = fmaf(in[u * DH + i], w[i * LCC + u], acc);
  float* dst = (tid >= 64 ? cv : ck);
  dst[((size_t)h * SC + c) * DH + o] = acc;
}

// ---------------- prep: V^T in bf16 + gate GEMV ----------------
__global__ __launch_bounds__(256) void nsa_prep_kernel(
    const float* __restrict__ q, const float* __restrict__ v,
    const float* __restrict__ wg,
    u16* __restrict__ vt, float* __restrict__ gates) {
  int id = blockIdx.x * 256 + threadIdx.x;   // 0..32767
  {  // Vt[h][d][s] bf16
    int h = id >> 14, d = (id >> 8) & 63, s8 = (id & 255) * 8;
    union { uint4 qv; u16 u[8]; } P;
    #pragma unroll
    for (int j = 0; j < 8; ++j)
      P.u[j] = f2bf(v[(size_t)(s8 + j) * (HKV * DH) + h * DH + d]);
    *(uint4*)(vt + ((size_t)h * 64 + d) * S_LEN + s8) = P.qv;
  }
  {  // gates[s][hq][e]
    int s = id >> 4, hq = id & 15;
    const float4* qp = (const float4*)(q + ((size_t)s * HQ + hq) * DH);
    const float4* w0 = (const float4*)(wg);
    const float4* w1 = (const float4*)(wg + DH);
    const float4* w2 = (const float4*)(wg + 2 * DH);
    float g0 = 0.f, g1 = 0.f, g2 = 0.f;
    #pragma unroll
    for (int i = 0; i < 16; ++i) {
      float4 a = qp[i];
      float4 b0 = w0[i], b1 = w1[i], b2 = w2[i];
      g0 += a.x*b0.x + a.y*b0.y + a.z*b0.z + a.w*b0.w;
      g1 += a.x*b1.x + a.y*b1.y + a.z*b1.z + a.w*b1.w;
      g2 += a.x*b2.x + a.y*b2.y + a.z*b2.z + a.w*b2.w;
    }
    float* gp = gates + ((size_t)s * HQ + hq) * 3;
    gp[0] = g0; gp[1] = g1; gp[2] = g2;
  }
}

// ---- Stage B: compressed attention + pooling + top-8 selection (exact f32) ----
__global__ __launch_bounds__(256) void nsa_cmp_kernel(
    const float* __restrict__ q, const float* __restrict__ wg,
    const float* __restrict__ ck, const float* __restrict__ cv,
    float* __restrict__ out, int* __restrict__ sel) {
  int h  = blockIdx.x / (S_LEN / QT);
  int s0 = (blockIdx.x % (S_LEN / QT)) * QT;
  int tid = threadIdx.x;
  __shared__ float sck[SC * DH];      // K rows, float4-swizzled
  __shared__ float scv[SC * DH];      // V rows, plain
  __shared__ float qs[GQ * DH];
  __shared__ float sc[GQ][SCP2];
  __shared__ float pkv[SC + 1];
  __shared__ float gsh[GQ];
  __shared__ float red[GQ * DH];

  float4* sck4 = (float4*)sck;
  float4* scv4 = (float4*)scv;
  const float4* qs4 = (const float4*)qs;

  for (int f = tid; f < SC * 16; f += 256) {
    int c = f >> 4, c4 = f & 15;
    float4 kk = ((const float4*)(ck + (size_t)h * SC * DH))[f];
    float4 vv = ((const float4*)(cv + (size_t)h * SC * DH))[f];
    sck4[(c << 4) | (c4 ^ (c & 7))] = kk;
    scv4[f] = vv;
  }

  int d4 = tid & 15, gi2 = (tid >> 4) & 7, half = tid >> 7;

  for (int qq = 0; qq < QT; ++qq) {
    int s = s0 + qq;
    for (int f = tid; f < GQ * DH / 4; f += 256)
      ((float4*)qs)[f] = ((const float4*)(q + ((size_t)s * HQ + h * GQ) * DH))[f];
    __syncthreads();
    if (tid < GQ) {   // gate e=2 (cmp)
      float d = 0.f;
      for (int dd = 0; dd < DH; ++dd) d = fmaf(qs[tid * DH + dd], wg[2 * DH + dd], d);
      gsh[tid] = d;
    }
    int nc = (s >= LCC - 1) ? ((s - (LCC - 1)) >> 4) + 1 : 0;

    {
      int c = tid & 127, hg = tid >> 7;
      if (c < SC) {
        float d0 = 0.f, d1 = 0.f, d2 = 0.f, d3 = 0.f;
        if (c < nc) {
          const float4* q0 = qs4 + (hg * 4 + 0) * 16;
          const float4* q1 = qs4 + (hg * 4 + 1) * 16;
          const float4* q2 = qs4 + (hg * 4 + 2) * 16;
          const float4* q3 = qs4 + (hg * 4 + 3) * 16;
          #pragma unroll
          for (int cc = 0; cc < 16; ++cc) {
            float4 kk = sck4[(c << 4) | (cc ^ (c & 7))];
            float4 a = q0[cc], b = q1[cc], e = q2[cc], ff = q3[cc];
            d0 = fmaf(kk.x, a.x, d0); d0 = fmaf(kk.y, a.y, d0); d0 = fmaf(kk.z, a.z, d0); d0 = fmaf(kk.w, a.w, d0);
            d1 = fmaf(kk.x, b.x, d1); d1 = fmaf(kk.y, b.y, d1); d1 = fmaf(kk.z, b.z, d1); d1 = fmaf(kk.w, b.w, d1);
            d2 = fmaf(kk.x, e.x, d2); d2 = fmaf(kk.y, e.y, d2); d2 = fmaf(kk.z, e.z, d2); d2 = fmaf(kk.w, e.w, d2);
            d3 = fmaf(kk.x, ff.x, d3); d3 = fmaf(kk.y, ff.y, d3); d3 = fmaf(kk.z, ff.z, d3); d3 = fmaf(kk.w, ff.w, d3);
          }
        }
        float m0 = (c < nc) ? SCALE : 0.f;
        float ninf = (c < nc) ? 0.f : -INFINITY;
        sc[hg * 4 + 0][c] = d0 * m0 + ninf;
        sc[hg * 4 + 1][c] = d1 * m0 + ninf;
        sc[hg * 4 + 2][c] = d2 * m0 + ninf;
        sc[hg * 4 + 3][c] = d3 * m0 + ninf;
      }
    }
    __syncthreads();

    {
      int gi = tid >> 5, j = tid & 31;
      float m = -INFINITY;
      for (int c = j; c < SC; c += 32) m = fmaxf(m, sc[gi][c]);
      for (int off = 16; off; off >>= 1) m = fmaxf(m, __shfl_xor(m, off, 32));
      m = fmaxf(m, -1e30f);
      float ssum = 0.f;
      for (int c = j; c < SC; c += 32) {
        float p = expf(sc[gi][c] - m);
        sc[gi][c] = p; ssum += p;
      }
      for (int off = 16; off; off >>= 1) ssum += __shfl_xor(ssum, off, 32);
      float inv = 1.f / fmaxf(ssum, 1e-20f);
      for (int c = j; c < SC; c += 32) sc[gi][c] *= inv;
    }
    __syncthreads();

    if (tid < SC) {
      float t = 0.f;
      for (int gi = 0; gi < GQ; ++gi) t += sc[gi][tid];
      pkv[tid] = t;
    }
    __syncthreads();

    if (tid < 32) {
      float pv;
      if (tid < NOUT) {
        float t = 0.f;
        #pragma unroll
        for (int u = 0; u < 5; ++u) t += pkv[tid * 4 + u];
        pv = t * 0.2f;
      } else pv = -1.0f;
      if (tid == (s >> 6)) pv = INFINITY;
      int* dst = sel + ((size_t)h * S_LEN + s) * KSEL;
      #pragma unroll
      for (int kk = 0; kk < KSEL; ++kk) {
        float v0 = pv; int i0 = tid;
        #pragma unroll
        for (int off = 16; off; off >>= 1) {
          float v1 = __shfl_xor(v0, off, 32);
          int   i1 = __shfl_xor(i0, off, 32);
          if (v1 > v0 || (v1 == v0 && i1 < i0)) { v0 = v1; i0 = i1; }
        }
        if (tid == 0) dst[kk] = i0;
        if (tid == i0) pv = -INFINITY;
      }
    }

    {
      float4 acc = {0.f, 0.f, 0.f, 0.f};
      for (int c = half; c < nc; c += 2) {
        float p = sc[gi2][c];
        float4 vv = scv4[(c << 4) | d4];
        acc.x = fmaf(p, vv.x, acc.x);
        acc.y = fmaf(p, vv.y, acc.y);
        acc.z = fmaf(p, vv.z, acc.z);
        acc.w = fmaf(p, vv.w, acc.w);
      }
      if (half == 1) ((float4*)red)[gi2 * 16 + d4] = acc;
      __syncthreads();
      if (half == 0) {
        float4 o = ((float4*)red)[gi2 * 16 + d4];
        acc.x += o.x; acc.y += o.y; acc.z += o.z; acc.w += o.w;
        float g = gsh[gi2];
        float4* op = (float4*)(out + ((size_t)s * HQ + h * GQ + gi2) * DH) + d4;
        float4 ov;
        ov.x = g * acc.x; ov.y = g * acc.y; ov.z = g * acc.z; ov.w = g * acc.w;
        *op = ov;
      }
    }
    __syncthreads();
  }
}

// ---------------- merged sel + swa attention, MFMA bf16 ----------------
// LDS swizzle: elem(row, c) = row*64 + (c ^ ((row&7)<<3))  (bf16 elements)
__device__ __forceinline__ void attn_chunk(
    int cb, int lo_l, bool selb, int tid, int l, int s_lane,
    const bf16x8* qf, const float* __restrict__ kg, const u16* __restrict__ vtg,
    short* kT, short* vT, short* pTw,
    f32x4 (&o)[4], float& mrun, float& lsum) {
  // ---- stage K (f32->bf16) and V^T (pre-transposed bf16) ----
  #pragma unroll
  for (int i = 0; i < 2; ++i) {
    int tt = i * 256 + tid;
    int oc8 = (tt & 7) * 8;
    int row = tt >> 3;               // key for K, d for V^T
    {
      int srow = cb + row; if (srow > S_LEN - 1) srow = S_LEN - 1;
      const float4* gp = (const float4*)(kg + (size_t)srow * (HKV * DH) + oc8);
      float4 a = gp[0], b = gp[1];
      union { uint4 qv; u16 u[8]; } P;
      P.u[0] = f2bf(a.x); P.u[1] = f2bf(a.y); P.u[2] = f2bf(a.z); P.u[3] = f2bf(a.w);
      P.u[4] = f2bf(b.x); P.u[5] = f2bf(b.y); P.u[6] = f2bf(b.z); P.u[7] = f2bf(b.w);
      *(uint4*)(&kT[(row << 6) | (oc8 ^ ((row & 7) << 3))]) = P.qv;
    }
    {
      int koff = cb + oc8; if (koff > S_LEN - 8) koff = S_LEN - 8;
      uint4 wv = *(const uint4*)(vtg + (size_t)row * S_LEN + koff);
      *(uint4*)(&vT[(row << 6) | (oc8 ^ ((row & 7) << 3))]) = wv;
    }
  }
  __syncthreads();

  int col = l & 15;
  int lg8 = (l >> 4) << 3;
  int kq  = (l >> 4) << 2;
  int xr  = (l & 7) << 3;

  // ---- S^T = K · Q^T ----
  f32x4 st[4];
  #pragma unroll
  for (int mt = 0; mt < 4; ++mt) st[mt] = (f32x4){0.f, 0.f, 0.f, 0.f};
  #pragma unroll
  for (int ks = 0; ks < 2; ++ks) {
    int co = (ks * 32 + lg8) ^ xr;
    #pragma unroll
    for (int mt = 0; mt < 4; ++mt) {
      bf16x8 kf = *(const bf16x8*)(&kT[((mt * 16 + col) << 6) | co]);
      st[mt] = __builtin_amdgcn_mfma_f32_16x16x32_bf16(kf, qf[ks], st[mt], 0, 0, 0);
    }
  }

  // ---- mask + online softmax (per col q, lane-local state) ----
  float mc = -INFINITY;
  #pragma unroll
  for (int mt = 0; mt < 4; ++mt) {
    #pragma unroll
    for (int r = 0; r < 4; ++r) {
      int key = cb + mt * 16 + kq + r;
      bool vis = selb && (key >= lo_l) && (key <= s_lane);
      float x = vis ? st[mt][r] * SCALE : -INFINITY;
      st[mt][r] = x;
      mc = fmaxf(mc, x);
    }
  }
  mc = fmaxf(mc, __shfl_xor(mc, 16));
  mc = fmaxf(mc, __shfl_xor(mc, 32));
  float mn = fmaxf(fmaxf(mrun, mc), -1e30f);
  float fr = __expf(mrun - mn);
  float ps = 0.f;
  #pragma unroll
  for (int mt = 0; mt < 4; ++mt) {
    #pragma unroll
    for (int r = 0; r < 4; ++r) {
      float p = __expf(st[mt][r] - mn);
      st[mt][r] = p; ps += p;
    }
  }
  ps += __shfl_xor(ps, 16);
  ps += __shfl_xor(ps, 32);
  lsum = lsum * fr + ps;
  mrun = mn;
  #pragma unroll
  for (int mt = 0; mt < 4; ++mt) o[mt] *= fr;

  // ---- P -> bf16 -> per-wave LDS ----
  int pc = col << 6;
  #pragma unroll
  for (int mt = 0; mt < 4; ++mt) {
    #pragma unroll
    for (int pr = 0; pr < 2; ++pr) {
      int key = mt * 16 + kq + pr * 2;
      u32 pk = (u32)f2bf(st[mt][pr * 2]) | ((u32)f2bf(st[mt][pr * 2 + 1]) << 16);
      *(u32*)(&pTw[pc | (key ^ xr)]) = pk;
    }
  }

  // ---- O^T += V^T · P ----
  #pragma unroll
  for (int ks = 0; ks < 2; ++ks) {
    int co = (ks * 32 + lg8) ^ xr;
    bf16x8 pf = *(const bf16x8*)(&pTw[pc | co]);
    #pragma unroll
    for (int mt = 0; mt < 4; ++mt) {
      bf16x8 vf = *(const bf16x8*)(&vT[((mt * 16 + col) << 6) | co]);
      o[mt] = __builtin_amdgcn_mfma_f32_16x16x32_bf16(vf, pf, o[mt], 0, 0, 0);
    }
  }
  __syncthreads();
}

__global__ __launch_bounds__(256) void nsa_selswa_kernel(
    const float* __restrict__ q, const float* __restrict__ k,
    const u16* __restrict__ vt, const float* __restrict__ gates,
    const int* __restrict__ sel, float* __restrict__ out) {
  int bid = blockIdx.x;
  int h  = bid >> 8;
  int s0 = (bid & 255) * QTS;
  int tid = threadIdx.x;
  int w = tid >> 6, l = tid & 63;
  __shared__ __align__(16) short kT[64 * 64];
  __shared__ __align__(16) short vT[64 * 64];
  __shared__ __align__(16) short pT[4][16 * 64];
  __shared__ int selsh[64];

  if (tid < 64)
    selsh[tid] = sel[((size_t)h * S_LEN + s0 + (tid >> 3)) * KSEL + (tid & 7)];

  int col = l & 15, qq = col & 7, gh2 = col >> 3;
  int s_lane = s0 + qq;
  size_t qrow = (size_t)s_lane * HQ + h * 8 + w * 2 + gh2;

  // Q fragments (B-operand layout: n=col, k-runs of 8)
  bf16x8 qf[2];
  #pragma unroll
  for (int ks = 0; ks < 2; ++ks) {
    const float4* gp = (const float4*)(q + qrow * DH + ks * 32 + ((l >> 4) << 3));
    float4 a = gp[0], b = gp[1];
    union { bf16x8 v; u16 u[8]; } P;
    P.u[0] = f2bf(a.x); P.u[1] = f2bf(a.y); P.u[2] = f2bf(a.z); P.u[3] = f2bf(a.w);
    P.u[4] = f2bf(b.x); P.u[5] = f2bf(b.y); P.u[6] = f2bf(b.z); P.u[7] = f2bf(b.w);
    qf[ks] = P.v;
  }
  float gsel = gates[qrow * 3 + 0];
  float gswa = gates[qrow * 3 + 1];
  __syncthreads();

  u32 qmask = 0;
  #pragma unroll
  for (int j = 0; j < 8; ++j) qmask |= 1u << selsh[qq * 8 + j];
  u32 un = qmask;
  un |= (u32)__shfl_xor((int)un, 1);
  un |= (u32)__shfl_xor((int)un, 2);
  un |= (u32)__shfl_xor((int)un, 4);

  const float* kg = k + h * DH;
  const u16* vtg = vt + (size_t)h * 64 * S_LEN;
  short* pTw = pT[w];

  f32x4 o[4];
  f32x4 res[4];
  float mrun, lsum;

  // ---- SEL pass over union of selected blocks ----
  #pragma unroll
  for (int mt = 0; mt < 4; ++mt) o[mt] = (f32x4){0.f, 0.f, 0.f, 0.f};
  mrun = -INFINITY; lsum = 0.f;
  for (int b = 0; b < NB; ++b) {
    if (!((un >> b) & 1)) continue;
    attn_chunk(b * LB, 0, (qmask >> b) & 1, tid, l, s_lane,
               qf, kg, vtg, kT, vT, pTw, o, mrun, lsum);
  }
  {
    float gv = gsel / fmaxf(lsum, 1e-20f);
    #pragma unroll
    for (int mt = 0; mt < 4; ++mt) res[mt] = o[mt] * gv;
  }

  // ---- SWA pass ----
  #pragma unroll
  for (int mt = 0; mt < 4; ++mt) o[mt] = (f32x4){0.f, 0.f, 0.f, 0.f};
  mrun = -INFINITY; lsum = 0.f;
  int t0 = s0 - (WIN - 1); if (t0 < 0) t0 = 0;
  int lo_l = s_lane - (WIN - 1);
  for (int cb = (t0 & ~63); cb <= s0 + QTS - 1; cb += 64)
    attn_chunk(cb, lo_l, true, tid, l, s_lane,
               qf, kg, vtg, kT, vT, pTw, o, mrun, lsum);
  {
    float gv = gswa / fmaxf(lsum, 1e-20f);
    #pragma unroll
    for (int mt = 0; mt < 4; ++mt) res[mt] += o[mt] * gv;
  }

  // ---- write out (RMW; cmp wrote '=' earlier) ----
  int kq = (l >> 4) << 2;
  #pragma unroll
  for (int mt = 0; mt < 4; ++mt) {
    float4* op = (float4*)(out + qrow * DH + mt * 16 + kq);
    float4 pv = *op;
    pv.x += res[mt][0]; pv.y += res[mt][1];
    pv.z += res[mt][2]; pv.w += res[mt][3];
    *op = pv;
  }
}

extern "C" void kernel_launch(void* const* d_in, const int* in_sizes, int n_in,
                              void* d_out, int out_size, void* d_ws, size_t ws_size,
                              hipStream_t stream) {
  const float* q  = (const float*)d_in[0];
  const float* k  = (const float*)d_in[1];
  const float* v  = (const float*)d_in[2];
  const float* wk = (const float*)d_in[3];
  const float* wv = (const float*)d_in[4];
  const float* wg = (const float*)d_in[5];
  float* out = (float*)d_out;

  float* ck    = (float*)d_ws;
  float* cv    = ck + (size_t)HKV * SC * DH;
  float* gates = cv + (size_t)HKV * SC * DH;
  int*   sel   = (int*)(gates + (size_t)S_LEN * HQ * 3);
  u16*   vt    = (u16*)(sel + (size_t)HKV * S_LEN * KSEL);

  nsa_conv_kernel<<<HKV * SC, 128, 0, stream>>>(k, v, wk, wv, ck, cv);
  nsa_prep_kernel<<<128, 256, 0, stream>>>(q, v, wg, vt, gates);
  nsa_cmp_kernel<<<HKV * (S_LEN / QT), 256, 0, stream>>>(q, wg, ck, cv, out, sel);
  nsa_selswa_kernel<<<HKV * (S_LEN / QTS), 256, 0, stream>>>(q, k, vt, gates, sel, out);
}

// Round 6
// 246.771 us; speedup vs baseline: 3.9480x; 1.1107x over previous
//
#include <hip/hip_runtime.h>
#include <hip/hip_bf16.h>
#include <math.h>

#define S_LEN  2048
#define HQ     16
#define HKV    2
#define GQ     8      // Hq / Hkv
#define DH     64
#define LCC    32     // compression block
#define CSTRIDE 16
#define SC     127    // (S - LC)/STRIDE + 1
#define LB     64     // selection block
#define KSEL   8
#define WIN    512
#define NB     32     // S / LB
#define NOUT   31     // pooled length before pad
#define QT     4      // queries per block in cmp kernel
#define QTS    8      // queries per block in selswa kernel
#define SCALE  0.125f
#define SCP2   132    // padded score row (cmp)

typedef __attribute__((ext_vector_type(8))) short bf16x8;
typedef __attribute__((ext_vector_type(4))) float f32x4;
typedef unsigned short u16;
typedef unsigned int   u32;

__device__ __forceinline__ u16 f2bf(float f) {
  u32 u = __float_as_uint(f);
  return (u16)((u + 0x7FFFu + ((u >> 16) & 1u)) >> 16);
}

__device__ __forceinline__ void gl_lds16(const void* g, void* lds) {
  __builtin_amdgcn_global_load_lds(
      (const __attribute__((address_space(1))) void*)g,
      (__attribute__((address_space(3))) void*)lds, 16, 0, 0);
}

// ---------------- Stage A: conv1d compression (split-K, 256 thr) ----------------
__global__ __launch_bounds__(256) void nsa_conv_kernel(
    const float* __restrict__ k, const float* __restrict__ v,
    const float* __restrict__ wk, const float* __restrict__ wv,
    float* __restrict__ ck, float* __restrict__ cv) {
  int c = blockIdx.x % SC;
  int h = blockIdx.x / SC;
  __shared__ float kin[LCC * DH];
  __shared__ float vin[LCC * DH];
  __shared__ float cred[128];
  int tid = threadIdx.x;
  for (int f = tid; f < LCC * DH / 4; f += 256) {
    int tt = f >> 4, i4 = f & 15;
    int row = c * CSTRIDE + tt;
    ((float4*)kin)[f] = ((const float4*)(k + ((size_t)row * HKV + h) * DH))[i4];
    ((float4*)vin)[f] = ((const float4*)(v + ((size_t)row * HKV + h) * DH))[i4];
  }
  __syncthreads();
  int o  = tid & 63;
  int kv = (tid >> 6) & 1;   // 0:k 1:v
  int uh = tid >> 7;         // u half
  const float* w  = (kv ? wv : wk) + (size_t)o * (DH * LCC) + uh * 16;
  const float* in = (kv ? vin : kin) + uh * 16 * DH;
  float acc = 0.f;
  for (int i = 0; i < DH; ++i) {
    #pragma unroll
    for (int u = 0; u < 16; ++u)
      acc = fmaf(in[u * DH + i], w[i * LCC + u], acc);
  }
  if (uh == 1) cred[tid & 127] = acc;
  __syncthreads();
  if (uh == 0) {
    acc += cred[tid & 127];
    float* dst = (kv ? cv : ck);
    dst[((size_t)h * SC + c) * DH + o] = acc;
  }
}

// ---- prep: pre-swizzled bf16 K + V^T (for global_load_lds staging) + gates ----
// kb[h][s][d ^ ((s&7)<<3)]  (row-contiguous 128B rows)
// vt[h][d][(s&~63) | ((s&63) ^ ((d&7)<<3))]
__global__ __launch_bounds__(256) void nsa_prep_kernel(
    const float* __restrict__ q, const float* __restrict__ k,
    const float* __restrict__ v, const float* __restrict__ wg,
    u16* __restrict__ kb, u16* __restrict__ vt, float* __restrict__ gates) {
  int id = blockIdx.x * 256 + threadIdx.x;   // 0..32767
  {  // kb item: (h, s, d8)
    int h = id >> 14, s = (id >> 3) & 2047, d8 = (id & 7) << 3;
    const float4* gp = (const float4*)(k + ((size_t)s * HKV + h) * DH + d8);
    float4 a = gp[0], b = gp[1];
    union { uint4 qv; u16 u[8]; } P;
    P.u[0]=f2bf(a.x); P.u[1]=f2bf(a.y); P.u[2]=f2bf(a.z); P.u[3]=f2bf(a.w);
    P.u[4]=f2bf(b.x); P.u[5]=f2bf(b.y); P.u[6]=f2bf(b.z); P.u[7]=f2bf(b.w);
    *(uint4*)(kb + ((size_t)h * S_LEN + s) * 64 + (d8 ^ ((s & 7) << 3))) = P.qv;
  }
  {  // vt item: (h, d, s8)
    int h = id >> 14, d = (id >> 8) & 63, s8 = (id & 255) << 3;
    union { uint4 qv; u16 u[8]; } P;
    #pragma unroll
    for (int j = 0; j < 8; ++j)
      P.u[j] = f2bf(v[(size_t)(s8 + j) * (HKV * DH) + h * DH + d]);
    int dst = (s8 & ~63) | ((s8 & 63) ^ ((d & 7) << 3));
    *(uint4*)(vt + ((size_t)h * 64 + d) * S_LEN + dst) = P.qv;
  }
  {  // gates[s][hq][e]
    int s = id >> 4, hq = id & 15;
    const float4* qp = (const float4*)(q + ((size_t)s * HQ + hq) * DH);
    const float4* w0 = (const float4*)(wg);
    const float4* w1 = (const float4*)(wg + DH);
    const float4* w2 = (const float4*)(wg + 2 * DH);
    float g0 = 0.f, g1 = 0.f, g2 = 0.f;
    #pragma unroll
    for (int i = 0; i < 16; ++i) {
      float4 a = qp[i];
      float4 b0 = w0[i], b1 = w1[i], b2 = w2[i];
      g0 += a.x*b0.x + a.y*b0.y + a.z*b0.z + a.w*b0.w;
      g1 += a.x*b1.x + a.y*b1.y + a.z*b1.z + a.w*b1.w;
      g2 += a.x*b2.x + a.y*b2.y + a.z*b2.z + a.w*b2.w;
    }
    float* gp = gates + ((size_t)s * HQ + hq) * 3;
    gp[0] = g0; gp[1] = g1; gp[2] = g2;
  }
}

// ---- Stage B: compressed attn + pooling + exact top-8 (f32, K in registers) ----
__global__ __launch_bounds__(256) void nsa_cmp_kernel(
    const float* __restrict__ q, const float* __restrict__ ck,
    const float* __restrict__ cv, const float* __restrict__ gates,
    float* __restrict__ out, int* __restrict__ sel) {
  int h  = blockIdx.x / (S_LEN / QT);
  int s0 = (blockIdx.x % (S_LEN / QT)) * QT;
  int tid = threadIdx.x;
  __shared__ float qs[GQ * DH];
  __shared__ float sc[GQ][SCP2];
  __shared__ float pkv[SC + 1];
  __shared__ float red[GQ * DH];
  __shared__ float gsh[GQ];
  const float4* qs4 = (const float4*)qs;

  int cc0 = tid & 127;
  int c   = (cc0 < SC) ? cc0 : SC - 1;
  bool cval = cc0 < SC;
  int hg = tid >> 7;
  float4 kr[16];                      // K row in registers (exact f32)
  {
    const float4* kp = (const float4*)(ck + ((size_t)h * SC + c) * DH);
    #pragma unroll
    for (int i = 0; i < 16; ++i) kr[i] = kp[i];
  }
  int d4 = tid & 15, gi2 = (tid >> 4) & 7, half = tid >> 7;

  for (int qq = 0; qq < QT; ++qq) {
    int s = s0 + qq;
    for (int f = tid; f < GQ * 16; f += 256)
      ((float4*)qs)[f] = ((const float4*)(q + ((size_t)s * HQ + h * GQ) * DH))[f];
    __syncthreads();
    int nc = (s >= LCC - 1) ? ((s - (LCC - 1)) >> 4) + 1 : 0;

    // scores: thread (c, 4 heads); q via wave-uniform LDS broadcast
    {
      float d0=0.f, d1=0.f, d2=0.f, d3=0.f;
      const float4* q0 = qs4 + (hg*4+0)*16;
      const float4* q1 = qs4 + (hg*4+1)*16;
      const float4* q2 = qs4 + (hg*4+2)*16;
      const float4* q3 = qs4 + (hg*4+3)*16;
      #pragma unroll
      for (int i = 0; i < 16; ++i) {
        float4 kk = kr[i];
        float4 a = q0[i], b = q1[i], e = q2[i], f4 = q3[i];
        d0 = fmaf(kk.x,a.x,d0); d0 = fmaf(kk.y,a.y,d0); d0 = fmaf(kk.z,a.z,d0); d0 = fmaf(kk.w,a.w,d0);
        d1 = fmaf(kk.x,b.x,d1); d1 = fmaf(kk.y,b.y,d1); d1 = fmaf(kk.z,b.z,d1); d1 = fmaf(kk.w,b.w,d1);
        d2 = fmaf(kk.x,e.x,d2); d2 = fmaf(kk.y,e.y,d2); d2 = fmaf(kk.z,e.z,d2); d2 = fmaf(kk.w,e.w,d2);
        d3 = fmaf(kk.x,f4.x,d3); d3 = fmaf(kk.y,f4.y,d3); d3 = fmaf(kk.z,f4.z,d3); d3 = fmaf(kk.w,f4.w,d3);
      }
      if (cval) {
        bool vis = cc0 < nc;
        float m0 = vis ? SCALE : 0.f;
        float ninf = vis ? 0.f : -INFINITY;
        sc[hg*4+0][cc0] = d0 * m0 + ninf;
        sc[hg*4+1][cc0] = d1 * m0 + ninf;
        sc[hg*4+2][cc0] = d2 * m0 + ninf;
        sc[hg*4+3][cc0] = d3 * m0 + ninf;
      }
    }
    if (tid < GQ) gsh[tid] = gates[((size_t)s * HQ + h * GQ + tid) * 3 + 2];
    __syncthreads();

    // softmax per head
    {
      int gi = tid >> 5, j = tid & 31;
      float m = -INFINITY;
      for (int cc = j; cc < SC; cc += 32) m = fmaxf(m, sc[gi][cc]);
      for (int off = 16; off; off >>= 1) m = fmaxf(m, __shfl_xor(m, off, 32));
      m = fmaxf(m, -1e30f);
      float ssum = 0.f;
      for (int cc = j; cc < SC; cc += 32) {
        float p = expf(sc[gi][cc] - m);
        sc[gi][cc] = p; ssum += p;
      }
      for (int off = 16; off; off >>= 1) ssum += __shfl_xor(ssum, off, 32);
      float inv = 1.f / fmaxf(ssum, 1e-20f);
      for (int cc = j; cc < SC; cc += 32) sc[gi][cc] *= inv;
    }
    __syncthreads();

    if (tid < SC) {
      float t = 0.f;
      #pragma unroll
      for (int gi = 0; gi < GQ; ++gi) t += sc[gi][tid];
      pkv[tid] = t;
    }
    __syncthreads();

    // pooled + exact top-8 (value desc, lowest index)
    if (tid < 32) {
      float pv;
      if (tid < NOUT) {
        float t = 0.f;
        #pragma unroll
        for (int u = 0; u < 5; ++u) t += pkv[tid * 4 + u];
        pv = t * 0.2f;
      } else pv = -1.0f;
      if (tid == (s >> 6)) pv = INFINITY;
      int* dst = sel + ((size_t)h * S_LEN + s) * KSEL;
      #pragma unroll
      for (int kk = 0; kk < KSEL; ++kk) {
        float v0 = pv; int i0 = tid;
        #pragma unroll
        for (int off = 16; off; off >>= 1) {
          float v1 = __shfl_xor(v0, off, 32);
          int   i1 = __shfl_xor(i0, off, 32);
          if (v1 > v0 || (v1 == v0 && i1 < i0)) { v0 = v1; i0 = i1; }
        }
        if (tid == 0) dst[kk] = i0;
        if (tid == i0) pv = -INFINITY;
      }
    }

    // PV: V rows streamed from L2 (cv is L2-resident), coalesced 256B/wave
    {
      float4 acc = {0.f, 0.f, 0.f, 0.f};
      const float4* vbase = (const float4*)(cv + (size_t)h * SC * DH) + d4;
      #pragma unroll 4
      for (int c2 = half; c2 < nc; c2 += 2) {
        float p = sc[gi2][c2];
        float4 vv = vbase[c2 * 16];
        acc.x = fmaf(p, vv.x, acc.x);
        acc.y = fmaf(p, vv.y, acc.y);
        acc.z = fmaf(p, vv.z, acc.z);
        acc.w = fmaf(p, vv.w, acc.w);
      }
      if (half == 1) ((float4*)red)[gi2 * 16 + d4] = acc;
      __syncthreads();
      if (half == 0) {
        float4 o = ((float4*)red)[gi2 * 16 + d4];
        acc.x += o.x; acc.y += o.y; acc.z += o.z; acc.w += o.w;
        float g = gsh[gi2];
        float4* op = (float4*)(out + ((size_t)s * HQ + h * GQ + gi2) * DH) + d4;
        float4 ov;
        ov.x = g * acc.x; ov.y = g * acc.y; ov.z = g * acc.z; ov.w = g * acc.w;
        *op = ov;
      }
    }
  }
}

// ---------------- merged sel + swa attention, MFMA bf16, DMA-staged ----------------
__device__ __forceinline__ void stage_chunk(const u16* kbh, const u16* vth,
                                            int cb, int w, int l,
                                            short* kT, short* vT) {
  #pragma unroll
  for (int r = 0; r < 2; ++r) {
    int seg = w * 2 + r;
    gl_lds16((const char*)kbh + (size_t)cb * 128 + seg * 1024 + l * 16,
             (char*)kT + seg * 1024);
    int drow = seg * 8 + (l >> 3);
    gl_lds16((const char*)vth + (size_t)drow * (S_LEN * 2) + cb * 2 + (l & 7) * 16,
             (char*)vT + seg * 1024);
  }
}

__device__ __forceinline__ void compute_chunk(
    const short* kT, const short* vT, short* pTw,
    int cb, int lo_l, bool selb, int l, int s_lane,
    const bf16x8 (&qf)[2], f32x4 (&o)[4], float& mrun, float& lsum) {
  int col = l & 15;
  int lg8 = (l >> 4) << 3;
  int kq  = (l >> 4) << 2;
  int xr  = (l & 7) << 3;

  // ---- S^T = K · Q^T ----
  f32x4 st[4];
  #pragma unroll
  for (int mt = 0; mt < 4; ++mt) st[mt] = (f32x4){0.f, 0.f, 0.f, 0.f};
  __builtin_amdgcn_s_setprio(1);
  #pragma unroll
  for (int ks = 0; ks < 2; ++ks) {
    int co = (ks * 32 + lg8) ^ xr;
    #pragma unroll
    for (int mt = 0; mt < 4; ++mt) {
      bf16x8 kf = *(const bf16x8*)(&kT[((mt * 16 + col) << 6) | co]);
      st[mt] = __builtin_amdgcn_mfma_f32_16x16x32_bf16(kf, qf[ks], st[mt], 0, 0, 0);
    }
  }
  __builtin_amdgcn_s_setprio(0);

  // ---- mask + online softmax ----
  float mc = -INFINITY;
  #pragma unroll
  for (int mt = 0; mt < 4; ++mt) {
    #pragma unroll
    for (int r = 0; r < 4; ++r) {
      int key = cb + mt * 16 + kq + r;
      bool vis = selb && (key >= lo_l) && (key <= s_lane);
      float x = vis ? st[mt][r] * SCALE : -INFINITY;
      st[mt][r] = x;
      mc = fmaxf(mc, x);
    }
  }
  mc = fmaxf(mc, __shfl_xor(mc, 16));
  mc = fmaxf(mc, __shfl_xor(mc, 32));
  float mn = fmaxf(fmaxf(mrun, mc), -1e30f);
  float fr = __expf(mrun - mn);
  float ps = 0.f;
  #pragma unroll
  for (int mt = 0; mt < 4; ++mt) {
    #pragma unroll
    for (int r = 0; r < 4; ++r) {
      float p = __expf(st[mt][r] - mn);
      st[mt][r] = p; ps += p;
    }
  }
  ps += __shfl_xor(ps, 16);
  ps += __shfl_xor(ps, 32);
  lsum = lsum * fr + ps;
  mrun = mn;
  #pragma unroll
  for (int mt = 0; mt < 4; ++mt) o[mt] *= fr;

  // ---- P -> bf16 -> per-wave LDS ----
  int pc = col << 6;
  #pragma unroll
  for (int mt = 0; mt < 4; ++mt) {
    #pragma unroll
    for (int pr = 0; pr < 2; ++pr) {
      int key = mt * 16 + kq + pr * 2;
      u32 pk = (u32)f2bf(st[mt][pr * 2]) | ((u32)f2bf(st[mt][pr * 2 + 1]) << 16);
      *(u32*)(&pTw[pc | (key ^ xr)]) = pk;
    }
  }

  // ---- O^T += V^T · P ----
  __builtin_amdgcn_s_setprio(1);
  #pragma unroll
  for (int ks = 0; ks < 2; ++ks) {
    int co = (ks * 32 + lg8) ^ xr;
    bf16x8 pf = *(const bf16x8*)(&pTw[pc | co]);
    #pragma unroll
    for (int mt = 0; mt < 4; ++mt) {
      bf16x8 vf = *(const bf16x8*)(&vT[((mt * 16 + col) << 6) | co]);
      o[mt] = __builtin_amdgcn_mfma_f32_16x16x32_bf16(vf, pf, o[mt], 0, 0, 0);
    }
  }
  __builtin_amdgcn_s_setprio(0);
}

__global__ __launch_bounds__(256) void nsa_selswa_kernel(
    const float* __restrict__ q, const u16* __restrict__ kb,
    const u16* __restrict__ vt, const float* __restrict__ gates,
    const int* __restrict__ sel, float* __restrict__ out) {
  int bid = blockIdx.x;
  int h  = bid >> 8;
  int s0 = (bid & 255) * QTS;
  int tid = threadIdx.x;
  int w = tid >> 6, l = tid & 63;
  __shared__ __align__(16) short kTb[2][64 * 64];
  __shared__ __align__(16) short vTb[2][64 * 64];
  __shared__ __align__(16) short pT[4][16 * 64];
  __shared__ int selsh[64];

  if (tid < 64)
    selsh[tid] = sel[((size_t)h * S_LEN + s0 + (tid >> 3)) * KSEL + (tid & 7)];

  int col = l & 15, qq = col & 7, gh2 = col >> 3;
  int s_lane = s0 + qq;
  size_t qrow = (size_t)s_lane * HQ + h * 8 + w * 2 + gh2;

  bf16x8 qf[2];
  #pragma unroll
  for (int ks = 0; ks < 2; ++ks) {
    const float4* gp = (const float4*)(q + qrow * DH + ks * 32 + ((l >> 4) << 3));
    float4 a = gp[0], b = gp[1];
    union { bf16x8 v; u16 u[8]; } P;
    P.u[0]=f2bf(a.x); P.u[1]=f2bf(a.y); P.u[2]=f2bf(a.z); P.u[3]=f2bf(a.w);
    P.u[4]=f2bf(b.x); P.u[5]=f2bf(b.y); P.u[6]=f2bf(b.z); P.u[7]=f2bf(b.w);
    qf[ks] = P.v;
  }
  float gsel = gates[qrow * 3 + 0];
  float gswa = gates[qrow * 3 + 1];
  __syncthreads();

  u32 qmask = 0;
  #pragma unroll
  for (int j = 0; j < 8; ++j) qmask |= 1u << selsh[qq * 8 + j];
  u32 un = qmask;
  un |= (u32)__shfl_xor((int)un, 1);
  un |= (u32)__shfl_xor((int)un, 2);
  un |= (u32)__shfl_xor((int)un, 4);

  const u16* kbh = kb + (size_t)h * S_LEN * 64;
  const u16* vth = vt + (size_t)h * 64 * S_LEN;
  short* pTw = pT[w];

  f32x4 o[4];
  f32x4 res[4];
  float mrun, lsum;

  // ---- SEL pass over union of selected blocks (1-deep DMA pipeline) ----
  #pragma unroll
  for (int mt = 0; mt < 4; ++mt) o[mt] = (f32x4){0.f, 0.f, 0.f, 0.f};
  mrun = -INFINITY; lsum = 0.f;
  {
    u32 rem = un;
    int cb = __builtin_ctz(rem) << 6;
    int par = 0;
    stage_chunk(kbh, vth, cb, w, l, kTb[0], vTb[0]);
    __syncthreads();
    while (1) {
      u32 rem2 = rem & (rem - 1);
      int cbn = rem2 ? (__builtin_ctz(rem2) << 6) : -1;
      if (cbn >= 0) stage_chunk(kbh, vth, cbn, w, l, kTb[par ^ 1], vTb[par ^ 1]);
      compute_chunk(kTb[par], vTb[par], pTw, cb, 0, (qmask >> (cb >> 6)) & 1,
                    l, s_lane, qf, o, mrun, lsum);
      __syncthreads();
      if (cbn < 0) break;
      rem = rem2; cb = cbn; par ^= 1;
    }
  }
  {
    float gv = gsel / fmaxf(lsum, 1e-20f);
    #pragma unroll
    for (int mt = 0; mt < 4; ++mt) res[mt] = o[mt] * gv;
  }

  // ---- SWA pass ----
  #pragma unroll
  for (int mt = 0; mt < 4; ++mt) o[mt] = (f32x4){0.f, 0.f, 0.f, 0.f};
  mrun = -INFINITY; lsum = 0.f;
  {
    int t0 = s0 - (WIN - 1); if (t0 < 0) t0 = 0;
    int lo_l = s_lane - (WIN - 1);
    int cbend = s0 + QTS - 1;
    int cb = t0 & ~63;
    int par = 0;
    stage_chunk(kbh, vth, cb, w, l, kTb[0], vTb[0]);
    __syncthreads();
    while (1) {
      int cbn = (cb + 64 <= cbend) ? cb + 64 : -1;
      if (cbn >= 0) stage_chunk(kbh, vth, cbn, w, l, kTb[par ^ 1], vTb[par ^ 1]);
      compute_chunk(kTb[par], vTb[par], pTw, cb, lo_l, true,
                    l, s_lane, qf, o, mrun, lsum);
      __syncthreads();
      if (cbn < 0) break;
      cb = cbn; par ^= 1;
    }
  }
  {
    float gv = gswa / fmaxf(lsum, 1e-20f);
    #pragma unroll
    for (int mt = 0; mt < 4; ++mt) res[mt] += o[mt] * gv;
  }

  // ---- write out (RMW; cmp wrote '=' earlier) ----
  int kq = (l >> 4) << 2;
  #pragma unroll
  for (int mt = 0; mt < 4; ++mt) {
    float4* op = (float4*)(out + qrow * DH + mt * 16 + kq);
    float4 pv = *op;
    pv.x += res[mt][0]; pv.y += res[mt][1];
    pv.z += res[mt][2]; pv.w += res[mt][3];
    *op = pv;
  }
}

extern "C" void kernel_launch(void* const* d_in, const int* in_sizes, int n_in,
                              void* d_out, int out_size, void* d_ws, size_t ws_size,
                              hipStream_t stream) {
  const float* q  = (const float*)d_in[0];
  const float* k  = (const float*)d_in[1];
  const float* v  = (const float*)d_in[2];
  const float* wk = (const float*)d_in[3];
  const float* wv = (const float*)d_in[4];
  const float* wg = (const float*)d_in[5];
  float* out = (float*)d_out;

  float* ck    = (float*)d_ws;                               // 16256 f
  float* cv    = ck + (size_t)HKV * SC * DH;                 // 16256 f
  float* gates = cv + (size_t)HKV * SC * DH;                 // 98304 f
  int*   sel   = (int*)(gates + (size_t)S_LEN * HQ * 3);     // 32768 i
  u16*   kb    = (u16*)(sel + (size_t)HKV * S_LEN * KSEL);   // 262144 u16
  u16*   vt    = kb + (size_t)HKV * S_LEN * DH;              // 262144 u16

  nsa_conv_kernel<<<HKV * SC, 256, 0, stream>>>(k, v, wk, wv, ck, cv);
  nsa_prep_kernel<<<128, 256, 0, stream>>>(q, k, v, wg, kb, vt, gates);
  nsa_cmp_kernel<<<HKV * (S_LEN / QT), 256, 0, stream>>>(q, ck, cv, gates, out, sel);
  nsa_selswa_kernel<<<HKV * (S_LEN / QTS), 256, 0, stream>>>(q, kb, vt, gates, sel, out);
}

// Round 7
// 207.865 us; speedup vs baseline: 4.6870x; 1.1872x over previous
//
#include <hip/hip_runtime.h>
#include <hip/hip_bf16.h>
#include <math.h>

#define S_LEN  2048
#define HQ     16
#define HKV    2
#define GQ     8      // Hq / Hkv
#define DH     64
#define LCC    32     // compression block
#define CSTRIDE 16
#define SC     127    // (S - LC)/STRIDE + 1
#define LB     64     // selection block
#define KSEL   8
#define WIN    512
#define NB     32     // S / LB
#define NOUT   31     // pooled length before pad
#define QTS    8      // queries per block in selswa kernel
#define SCALE  0.125f

typedef __attribute__((ext_vector_type(8))) short bf16x8;
typedef __attribute__((ext_vector_type(4))) float f32x4;
typedef unsigned short u16;
typedef unsigned int   u32;

__device__ __forceinline__ u16 f2bf(float f) {
  u32 u = __float_as_uint(f);
  return (u16)((u + 0x7FFFu + ((u >> 16) & 1u)) >> 16);
}

__device__ __forceinline__ void gl_lds16(const void* g, void* lds) {
  __builtin_amdgcn_global_load_lds(
      (const __attribute__((address_space(1))) void*)g,
      (__attribute__((address_space(3))) void*)lds, 16, 0, 0);
}

// ---------------- Stage A: conv1d compression (split-K, 256 thr) ----------------
__global__ __launch_bounds__(256) void nsa_conv_kernel(
    const float* __restrict__ k, const float* __restrict__ v,
    const float* __restrict__ wk, const float* __restrict__ wv,
    float* __restrict__ ck, float* __restrict__ cv) {
  int c = blockIdx.x % SC;
  int h = blockIdx.x / SC;
  __shared__ float kin[LCC * DH];
  __shared__ float vin[LCC * DH];
  __shared__ float cred[128];
  int tid = threadIdx.x;
  for (int f = tid; f < LCC * DH / 4; f += 256) {
    int tt = f >> 4, i4 = f & 15;
    int row = c * CSTRIDE + tt;
    ((float4*)kin)[f] = ((const float4*)(k + ((size_t)row * HKV + h) * DH))[i4];
    ((float4*)vin)[f] = ((const float4*)(v + ((size_t)row * HKV + h) * DH))[i4];
  }
  __syncthreads();
  int o  = tid & 63;
  int kv = (tid >> 6) & 1;   // 0:k 1:v
  int uh = tid >> 7;         // u half
  const float* w  = (kv ? wv : wk) + (size_t)o * (DH * LCC) + uh * 16;
  const float* in = (kv ? vin : kin) + uh * 16 * DH;
  float acc = 0.f;
  for (int i = 0; i < DH; ++i) {
    #pragma unroll
    for (int u = 0; u < 16; ++u)
      acc = fmaf(in[u * DH + i], w[i * LCC + u], acc);
  }
  if (uh == 1) cred[tid & 127] = acc;
  __syncthreads();
  if (uh == 0) {
    acc += cred[tid & 127];
    float* dst = (kv ? cv : ck);
    dst[((size_t)h * SC + c) * DH + o] = acc;
  }
}

// ---- prep: pre-swizzled bf16 K + V^T (for global_load_lds staging) + gates ----
// kb[h][s][d ^ ((s&7)<<3)]  (row-contiguous 128B rows)
// vt[h][d][(s&~63) | ((s&63) ^ ((d&7)<<3))]
__global__ __launch_bounds__(256) void nsa_prep_kernel(
    const float* __restrict__ q, const float* __restrict__ k,
    const float* __restrict__ v, const float* __restrict__ wg,
    u16* __restrict__ kb, u16* __restrict__ vt, float* __restrict__ gates) {
  int id = blockIdx.x * 256 + threadIdx.x;   // 0..32767
  {  // kb item: (h, s, d8)
    int h = id >> 14, s = (id >> 3) & 2047, d8 = (id & 7) << 3;
    const float4* gp = (const float4*)(k + ((size_t)s * HKV + h) * DH + d8);
    float4 a = gp[0], b = gp[1];
    union { uint4 qv; u16 u[8]; } P;
    P.u[0]=f2bf(a.x); P.u[1]=f2bf(a.y); P.u[2]=f2bf(a.z); P.u[3]=f2bf(a.w);
    P.u[4]=f2bf(b.x); P.u[5]=f2bf(b.y); P.u[6]=f2bf(b.z); P.u[7]=f2bf(b.w);
    *(uint4*)(kb + ((size_t)h * S_LEN + s) * 64 + (d8 ^ ((s & 7) << 3))) = P.qv;
  }
  {  // vt item: (h, d, s8)
    int h = id >> 14, d = (id >> 8) & 63, s8 = (id & 255) << 3;
    union { uint4 qv; u16 u[8]; } P;
    #pragma unroll
    for (int j = 0; j < 8; ++j)
      P.u[j] = f2bf(v[(size_t)(s8 + j) * (HKV * DH) + h * DH + d]);
    int dst = (s8 & ~63) | ((s8 & 63) ^ ((d & 7) << 3));
    *(uint4*)(vt + ((size_t)h * 64 + d) * S_LEN + dst) = P.qv;
  }
  {  // gates[s][hq][e]
    int s = id >> 4, hq = id & 15;
    const float4* qp = (const float4*)(q + ((size_t)s * HQ + hq) * DH);
    const float4* w0 = (const float4*)(wg);
    const float4* w1 = (const float4*)(wg + DH);
    const float4* w2 = (const float4*)(wg + 2 * DH);
    float g0 = 0.f, g1 = 0.f, g2 = 0.f;
    #pragma unroll
    for (int i = 0; i < 16; ++i) {
      float4 a = qp[i];
      float4 b0 = w0[i], b1 = w1[i], b2 = w2[i];
      g0 += a.x*b0.x + a.y*b0.y + a.z*b0.z + a.w*b0.w;
      g1 += a.x*b1.x + a.y*b1.y + a.z*b1.z + a.w*b1.w;
      g2 += a.x*b2.x + a.y*b2.y + a.z*b2.z + a.w*b2.w;
    }
    float* gp = gates + ((size_t)s * HQ + hq) * 3;
    gp[0] = g0; gp[1] = g1; gp[2] = g2;
  }
}

// ---- Stage B v3: wave-per-query compressed attn + pooling + exact top-8 ----
__global__ __launch_bounds__(256) void nsa_cmp_kernel(
    const float* __restrict__ q, const float* __restrict__ ck,
    const float* __restrict__ cv, const float* __restrict__ gates,
    float* __restrict__ out, int* __restrict__ sel) {
  int h  = blockIdx.x >> 9;          // / 512
  int s0 = (blockIdx.x & 511) << 2;  // * 4 queries, one per wave
  int tid = threadIdx.x;
  int w = tid >> 6, l = tid & 63;
  __shared__ float t4s[SC * DH];       // K (swizzled), then V (plain)
  __shared__ float pbuf[4][GQ][136];   // probs per wave-query; 136-stride = bank-clean
  __shared__ float pkvb[4][128];
  float4* t4 = (float4*)t4s;

  int s  = s0 + w;
  int hq = l >> 3, cg = l & 7;

  // stage K swizzled: slot (c<<4)|(i^(c&7))
  {
    const float4* ck4 = (const float4*)(ck + (size_t)h * SC * DH);
    for (int f = tid; f < SC * 16; f += 256) {
      int c = f >> 4, i = f & 15;
      t4[(c << 4) | (i ^ (c & 7))] = ck4[f];
    }
  }
  // q row for this lane's head into registers
  float4 q4[16];
  {
    const float4* qp = (const float4*)(q + ((size_t)s * HQ + h * GQ + hq) * DH);
    #pragma unroll
    for (int i = 0; i < 16; ++i) q4[i] = qp[i];
  }
  __syncthreads();

  int nc = (s >= LCC - 1) ? ((s - (LCC - 1)) >> 4) + 1 : 0;

  // scores: lane owns (head hq, cols cg+8t), wave-local softmax
  float p[16];
  float m = -INFINITY;
  #pragma unroll
  for (int t = 0; t < 16; ++t) {
    int c = cg + (t << 3);
    float d = 0.f;
    #pragma unroll
    for (int i = 0; i < 16; ++i) {
      float4 kk = t4[(c << 4) | (i ^ cg)];
      d = fmaf(kk.x, q4[i].x, d); d = fmaf(kk.y, q4[i].y, d);
      d = fmaf(kk.z, q4[i].z, d); d = fmaf(kk.w, q4[i].w, d);
    }
    float x = (c < nc) ? d * SCALE : -INFINITY;
    p[t] = x;
    m = fmaxf(m, x);
  }
  m = fmaxf(m, __shfl_xor(m, 1));
  m = fmaxf(m, __shfl_xor(m, 2));
  m = fmaxf(m, __shfl_xor(m, 4));
  m = fmaxf(m, -1e30f);
  float ssum = 0.f;
  #pragma unroll
  for (int t = 0; t < 16; ++t) { p[t] = expf(p[t] - m); ssum += p[t]; }
  ssum += __shfl_xor(ssum, 1);
  ssum += __shfl_xor(ssum, 2);
  ssum += __shfl_xor(ssum, 4);
  float inv = 1.f / fmaxf(ssum, 1e-20f);
  #pragma unroll
  for (int t = 0; t < 16; ++t) {
    p[t] *= inv;
    pbuf[w][hq][cg + (t << 3)] = p[t];
  }
  // head-sum for pooling (reduce over hq bits 3,4,5)
  #pragma unroll
  for (int t = 0; t < 16; ++t) {
    float v0 = p[t];
    v0 += __shfl_xor(v0, 8);
    v0 += __shfl_xor(v0, 16);
    v0 += __shfl_xor(v0, 32);
    p[t] = v0;
  }
  if (hq == 0) {
    #pragma unroll
    for (int t = 0; t < 16; ++t) pkvb[w][cg + (t << 3)] = p[t];
  }
  // pooled + exact top-8 (value desc, lowest index), lanes 0..31 of this wave
  if (l < 32) {
    float pv;
    if (l < NOUT) {
      float tt = 0.f;
      #pragma unroll
      for (int u = 0; u < 5; ++u) tt += pkvb[w][l * 4 + u];
      pv = tt * 0.2f;
    } else pv = -1.0f;
    if (l == (s >> 6)) pv = INFINITY;
    int* dst = sel + ((size_t)h * S_LEN + s) * KSEL;
    #pragma unroll
    for (int kk = 0; kk < KSEL; ++kk) {
      float v0 = pv; int i0 = l;
      #pragma unroll
      for (int off = 16; off; off >>= 1) {
        float v1 = __shfl_xor(v0, off, 32);
        int   i1 = __shfl_xor(i0, off, 32);
        if (v1 > v0 || (v1 == v0 && i1 < i0)) { v0 = v1; i0 = i1; }
      }
      if (l == 0) dst[kk] = i0;
      if (l == i0) pv = -INFINITY;
    }
  }
  __syncthreads();
  // stage V (plain rows)
  {
    const float4* cv4 = (const float4*)(cv + (size_t)h * SC * DH);
    for (int f = tid; f < SC * 16; f += 256) t4[f] = cv4[f];
  }
  __syncthreads();
  // PV: lane = (d-slice d4, head-pair hg2/hg2+4)
  {
    int d4 = l & 15, hg2 = l >> 4;
    float4 a0 = {0.f,0.f,0.f,0.f}, a1 = {0.f,0.f,0.f,0.f};
    #pragma unroll 2
    for (int c = 0; c < nc; ++c) {
      float4 vv = t4[(c << 4) | d4];
      float p0 = pbuf[w][hg2][c];
      float p1 = pbuf[w][hg2 + 4][c];
      a0.x = fmaf(p0, vv.x, a0.x); a0.y = fmaf(p0, vv.y, a0.y);
      a0.z = fmaf(p0, vv.z, a0.z); a0.w = fmaf(p0, vv.w, a0.w);
      a1.x = fmaf(p1, vv.x, a1.x); a1.y = fmaf(p1, vv.y, a1.y);
      a1.z = fmaf(p1, vv.z, a1.z); a1.w = fmaf(p1, vv.w, a1.w);
    }
    float g0 = gates[((size_t)s * HQ + h * GQ + hg2) * 3 + 2];
    float g1 = gates[((size_t)s * HQ + h * GQ + hg2 + 4) * 3 + 2];
    float4 o0, o1;
    o0.x = g0*a0.x; o0.y = g0*a0.y; o0.z = g0*a0.z; o0.w = g0*a0.w;
    o1.x = g1*a1.x; o1.y = g1*a1.y; o1.z = g1*a1.z; o1.w = g1*a1.w;
    ((float4*)(out + ((size_t)s * HQ + h * GQ + hg2) * DH))[d4] = o0;
    ((float4*)(out + ((size_t)s * HQ + h * GQ + hg2 + 4) * DH))[d4] = o1;
  }
}

// ---------------- merged sel + swa attention, MFMA bf16, DMA-staged ----------------
__device__ __forceinline__ void stage_chunk(const u16* kbh, const u16* vth,
                                            int cb, int w, int l,
                                            short* kT, short* vT) {
  #pragma unroll
  for (int r = 0; r < 2; ++r) {
    int seg = w * 2 + r;
    gl_lds16((const char*)kbh + (size_t)cb * 128 + seg * 1024 + l * 16,
             (char*)kT + seg * 1024);
    int drow = seg * 8 + (l >> 3);
    gl_lds16((const char*)vth + (size_t)drow * (S_LEN * 2) + cb * 2 + (l & 7) * 16,
             (char*)vT + seg * 1024);
  }
}

__device__ __forceinline__ void compute_chunk(
    const short* kT, const short* vT, short* pTw,
    int cb, int lo_l, bool selb, int l, int s_lane,
    const bf16x8 (&qf)[2], f32x4 (&o)[4], float& mrun, float& lsum) {
  int col = l & 15;
  int lg8 = (l >> 4) << 3;
  int kq  = (l >> 4) << 2;
  int xr  = (l & 7) << 3;

  // ---- S^T = K · Q^T ----
  f32x4 st[4];
  #pragma unroll
  for (int mt = 0; mt < 4; ++mt) st[mt] = (f32x4){0.f, 0.f, 0.f, 0.f};
  __builtin_amdgcn_s_setprio(1);
  #pragma unroll
  for (int ks = 0; ks < 2; ++ks) {
    int co = (ks * 32 + lg8) ^ xr;
    #pragma unroll
    for (int mt = 0; mt < 4; ++mt) {
      bf16x8 kf = *(const bf16x8*)(&kT[((mt * 16 + col) << 6) | co]);
      st[mt] = __builtin_amdgcn_mfma_f32_16x16x32_bf16(kf, qf[ks], st[mt], 0, 0, 0);
    }
  }
  __builtin_amdgcn_s_setprio(0);

  // ---- mask + online softmax ----
  float mc = -INFINITY;
  #pragma unroll
  for (int mt = 0; mt < 4; ++mt) {
    #pragma unroll
    for (int r = 0; r < 4; ++r) {
      int key = cb + mt * 16 + kq + r;
      bool vis = selb && (key >= lo_l) && (key <= s_lane);
      float x = vis ? st[mt][r] * SCALE : -INFINITY;
      st[mt][r] = x;
      mc = fmaxf(mc, x);
    }
  }
  mc = fmaxf(mc, __shfl_xor(mc, 16));
  mc = fmaxf(mc, __shfl_xor(mc, 32));
  float mn = fmaxf(fmaxf(mrun, mc), -1e30f);
  float fr = __expf(mrun - mn);
  float ps = 0.f;
  #pragma unroll
  for (int mt = 0; mt < 4; ++mt) {
    #pragma unroll
    for (int r = 0; r < 4; ++r) {
      float p = __expf(st[mt][r] - mn);
      st[mt][r] = p; ps += p;
    }
  }
  ps += __shfl_xor(ps, 16);
  ps += __shfl_xor(ps, 32);
  lsum = lsum * fr + ps;
  mrun = mn;
  #pragma unroll
  for (int mt = 0; mt < 4; ++mt) o[mt] *= fr;

  // ---- P -> bf16 -> per-wave LDS ----
  int pc = col << 6;
  #pragma unroll
  for (int mt = 0; mt < 4; ++mt) {
    #pragma unroll
    for (int pr = 0; pr < 2; ++pr) {
      int key = mt * 16 + kq + pr * 2;
      u32 pk = (u32)f2bf(st[mt][pr * 2]) | ((u32)f2bf(st[mt][pr * 2 + 1]) << 16);
      *(u32*)(&pTw[pc | (key ^ xr)]) = pk;
    }
  }

  // ---- O^T += V^T · P ----
  __builtin_amdgcn_s_setprio(1);
  #pragma unroll
  for (int ks = 0; ks < 2; ++ks) {
    int co = (ks * 32 + lg8) ^ xr;
    bf16x8 pf = *(const bf16x8*)(&pTw[pc | co]);
    #pragma unroll
    for (int mt = 0; mt < 4; ++mt) {
      bf16x8 vf = *(const bf16x8*)(&vT[((mt * 16 + col) << 6) | co]);
      o[mt] = __builtin_amdgcn_mfma_f32_16x16x32_bf16(vf, pf, o[mt], 0, 0, 0);
    }
  }
  __builtin_amdgcn_s_setprio(0);
}

__global__ __launch_bounds__(256) void nsa_selswa_kernel(
    const float* __restrict__ q, const u16* __restrict__ kb,
    const u16* __restrict__ vt, const float* __restrict__ gates,
    const int* __restrict__ sel, float* __restrict__ out) {
  int bid = blockIdx.x;
  int h  = bid >> 8;
  int s0 = (bid & 255) * QTS;
  int tid = threadIdx.x;
  int w = tid >> 6, l = tid & 63;
  __shared__ __align__(16) short kTb[2][64 * 64];
  __shared__ __align__(16) short vTb[2][64 * 64];
  __shared__ __align__(16) short pT[4][16 * 64];
  __shared__ int selsh[64];

  if (tid < 64)
    selsh[tid] = sel[((size_t)h * S_LEN + s0 + (tid >> 3)) * KSEL + (tid & 7)];

  int col = l & 15, qq = col & 7, gh2 = col >> 3;
  int s_lane = s0 + qq;
  size_t qrow = (size_t)s_lane * HQ + h * 8 + w * 2 + gh2;

  bf16x8 qf[2];
  #pragma unroll
  for (int ks = 0; ks < 2; ++ks) {
    const float4* gp = (const float4*)(q + qrow * DH + ks * 32 + ((l >> 4) << 3));
    float4 a = gp[0], b = gp[1];
    union { bf16x8 v; u16 u[8]; } P;
    P.u[0]=f2bf(a.x); P.u[1]=f2bf(a.y); P.u[2]=f2bf(a.z); P.u[3]=f2bf(a.w);
    P.u[4]=f2bf(b.x); P.u[5]=f2bf(b.y); P.u[6]=f2bf(b.z); P.u[7]=f2bf(b.w);
    qf[ks] = P.v;
  }
  float gsel = gates[qrow * 3 + 0];
  float gswa = gates[qrow * 3 + 1];
  __syncthreads();

  u32 qmask = 0;
  #pragma unroll
  for (int j = 0; j < 8; ++j) qmask |= 1u << selsh[qq * 8 + j];
  u32 un = qmask;
  un |= (u32)__shfl_xor((int)un, 1);
  un |= (u32)__shfl_xor((int)un, 2);
  un |= (u32)__shfl_xor((int)un, 4);

  const u16* kbh = kb + (size_t)h * S_LEN * 64;
  const u16* vth = vt + (size_t)h * 64 * S_LEN;
  short* pTw = pT[w];

  f32x4 o[4];
  f32x4 res[4];
  float mrun, lsum;

  // ---- SEL pass over union of selected blocks (1-deep DMA pipeline) ----
  #pragma unroll
  for (int mt = 0; mt < 4; ++mt) o[mt] = (f32x4){0.f, 0.f, 0.f, 0.f};
  mrun = -INFINITY; lsum = 0.f;
  {
    u32 rem = un;
    int cb = __builtin_ctz(rem) << 6;
    int par = 0;
    stage_chunk(kbh, vth, cb, w, l, kTb[0], vTb[0]);
    __syncthreads();
    while (1) {
      u32 rem2 = rem & (rem - 1);
      int cbn = rem2 ? (__builtin_ctz(rem2) << 6) : -1;
      if (cbn >= 0) stage_chunk(kbh, vth, cbn, w, l, kTb[par ^ 1], vTb[par ^ 1]);
      compute_chunk(kTb[par], vTb[par], pTw, cb, 0, (qmask >> (cb >> 6)) & 1,
                    l, s_lane, qf, o, mrun, lsum);
      __syncthreads();
      if (cbn < 0) break;
      rem = rem2; cb = cbn; par ^= 1;
    }
  }
  {
    float gv = gsel / fmaxf(lsum, 1e-20f);
    #pragma unroll
    for (int mt = 0; mt < 4; ++mt) res[mt] = o[mt] * gv;
  }

  // ---- SWA pass ----
  #pragma unroll
  for (int mt = 0; mt < 4; ++mt) o[mt] = (f32x4){0.f, 0.f, 0.f, 0.f};
  mrun = -INFINITY; lsum = 0.f;
  {
    int t0 = s0 - (WIN - 1); if (t0 < 0) t0 = 0;
    int lo_l = s_lane - (WIN - 1);
    int cbend = s0 + QTS - 1;
    int cb = t0 & ~63;
    int par = 0;
    stage_chunk(kbh, vth, cb, w, l, kTb[0], vTb[0]);
    __syncthreads();
    while (1) {
      int cbn = (cb + 64 <= cbend) ? cb + 64 : -1;
      if (cbn >= 0) stage_chunk(kbh, vth, cbn, w, l, kTb[par ^ 1], vTb[par ^ 1]);
      compute_chunk(kTb[par], vTb[par], pTw, cb, lo_l, true,
                    l, s_lane, qf, o, mrun, lsum);
      __syncthreads();
      if (cbn < 0) break;
      cb = cbn; par ^= 1;
    }
  }
  {
    float gv = gswa / fmaxf(lsum, 1e-20f);
    #pragma unroll
    for (int mt = 0; mt < 4; ++mt) res[mt] += o[mt] * gv;
  }

  // ---- write out (RMW; cmp wrote '=' earlier) ----
  int kq = (l >> 4) << 2;
  #pragma unroll
  for (int mt = 0; mt < 4; ++mt) {
    float4* op = (float4*)(out + qrow * DH + mt * 16 + kq);
    float4 pv = *op;
    pv.x += res[mt][0]; pv.y += res[mt][1];
    pv.z += res[mt][2]; pv.w += res[mt][3];
    *op = pv;
  }
}

extern "C" void kernel_launch(void* const* d_in, const int* in_sizes, int n_in,
                              void* d_out, int out_size, void* d_ws, size_t ws_size,
                              hipStream_t stream) {
  const float* q  = (const float*)d_in[0];
  const float* k  = (const float*)d_in[1];
  const float* v  = (const float*)d_in[2];
  const float* wk = (const float*)d_in[3];
  const float* wv = (const float*)d_in[4];
  const float* wg = (const float*)d_in[5];
  float* out = (float*)d_out;

  float* ck    = (float*)d_ws;                               // 16256 f
  float* cv    = ck + (size_t)HKV * SC * DH;                 // 16256 f
  float* gates = cv + (size_t)HKV * SC * DH;                 // 98304 f
  int*   sel   = (int*)(gates + (size_t)S_LEN * HQ * 3);     // 32768 i
  u16*   kb    = (u16*)(sel + (size_t)HKV * S_LEN * KSEL);   // 262144 u16
  u16*   vt    = kb + (size_t)HKV * S_LEN * DH;              // 262144 u16

  nsa_conv_kernel<<<HKV * SC, 256, 0, stream>>>(k, v, wk, wv, ck, cv);
  nsa_prep_kernel<<<128, 256, 0, stream>>>(q, k, v, wg, kb, vt, gates);
  nsa_cmp_kernel<<<HKV * (S_LEN / 4), 256, 0, stream>>>(q, ck, cv, gates, out, sel);
  nsa_selswa_kernel<<<HKV * (S_LEN / QTS), 256, 0, stream>>>(q, kb, vt, gates, sel, out);
}

// Round 9
// 190.574 us; speedup vs baseline: 5.1122x; 1.0907x over previous
//
#include <hip/hip_runtime.h>
#include <hip/hip_bf16.h>
#include <math.h>

#define S_LEN  2048
#define HQ     16
#define HKV    2
#define GQ     8      // Hq / Hkv
#define DH     64
#define LCC    32     // compression block
#define CSTRIDE 16
#define SC     127    // (S - LC)/STRIDE + 1
#define LB     64     // selection block
#define KSEL   8
#define WIN    512
#define NB     32     // S / LB
#define NOUT   31     // pooled length before pad
#define QTS    8      // queries per block in selswa kernel
#define SCALE  0.125f

typedef __attribute__((ext_vector_type(8))) short bf16x8;
typedef __attribute__((ext_vector_type(4))) float f32x4;
typedef unsigned short u16;
typedef unsigned int   u32;

__device__ __forceinline__ u16 f2bf(float f) {
  u32 u = __float_as_uint(f);
  return (u16)((u + 0x7FFFu + ((u >> 16) & 1u)) >> 16);
}

__device__ __forceinline__ void gl_lds16(const void* g, void* lds) {
  __builtin_amdgcn_global_load_lds(
      (const __attribute__((address_space(1))) void*)g,
      (__attribute__((address_space(3))) void*)lds, 16, 0, 0);
}

// ---------------- Stage A: conv1d compression (split-K, 256 thr) ----------------
__global__ __launch_bounds__(256) void nsa_conv_kernel(
    const float* __restrict__ k, const float* __restrict__ v,
    const float* __restrict__ wk, const float* __restrict__ wv,
    float* __restrict__ ck, float* __restrict__ cv) {
  int c = blockIdx.x % SC;
  int h = blockIdx.x / SC;
  __shared__ float kin[LCC * DH];
  __shared__ float vin[LCC * DH];
  __shared__ float cred[128];
  int tid = threadIdx.x;
  for (int f = tid; f < LCC * DH / 4; f += 256) {
    int tt = f >> 4, i4 = f & 15;
    int row = c * CSTRIDE + tt;
    ((float4*)kin)[f] = ((const float4*)(k + ((size_t)row * HKV + h) * DH))[i4];
    ((float4*)vin)[f] = ((const float4*)(v + ((size_t)row * HKV + h) * DH))[i4];
  }
  __syncthreads();
  int o  = tid & 63;
  int kv = (tid >> 6) & 1;   // 0:k 1:v
  int uh = tid >> 7;         // u half
  const float* w  = (kv ? wv : wk) + (size_t)o * (DH * LCC) + uh * 16;
  const float* in = (kv ? vin : kin) + uh * 16 * DH;
  float acc = 0.f;
  for (int i = 0; i < DH; ++i) {
    #pragma unroll
    for (int u = 0; u < 16; ++u)
      acc = fmaf(in[u * DH + i], w[i * LCC + u], acc);
  }
  if (uh == 1) cred[tid & 127] = acc;
  __syncthreads();
  if (uh == 0) {
    acc += cred[tid & 127];
    float* dst = (kv ? cv : ck);
    dst[((size_t)h * SC + c) * DH + o] = acc;
  }
}

// ---- prep: pre-swizzled bf16 K + V^T (for global_load_lds staging) + gates ----
__global__ __launch_bounds__(256) void nsa_prep_kernel(
    const float* __restrict__ q, const float* __restrict__ k,
    const float* __restrict__ v, const float* __restrict__ wg,
    u16* __restrict__ kb, u16* __restrict__ vt, float* __restrict__ gates) {
  int id = blockIdx.x * 256 + threadIdx.x;   // 0..32767
  {  // kb item: (h, s, d8)
    int h = id >> 14, s = (id >> 3) & 2047, d8 = (id & 7) << 3;
    const float4* gp = (const float4*)(k + ((size_t)s * HKV + h) * DH + d8);
    float4 a = gp[0], b = gp[1];
    union { uint4 qv; u16 u[8]; } P;
    P.u[0]=f2bf(a.x); P.u[1]=f2bf(a.y); P.u[2]=f2bf(a.z); P.u[3]=f2bf(a.w);
    P.u[4]=f2bf(b.x); P.u[5]=f2bf(b.y); P.u[6]=f2bf(b.z); P.u[7]=f2bf(b.w);
    *(uint4*)(kb + ((size_t)h * S_LEN + s) * 64 + (d8 ^ ((s & 7) << 3))) = P.qv;
  }
  {  // vt item: (h, d, s8)
    int h = id >> 14, d = (id >> 8) & 63, s8 = (id & 255) << 3;
    union { uint4 qv; u16 u[8]; } P;
    #pragma unroll
    for (int j = 0; j < 8; ++j)
      P.u[j] = f2bf(v[(size_t)(s8 + j) * (HKV * DH) + h * DH + d]);
    int dst = (s8 & ~63) | ((s8 & 63) ^ ((d & 7) << 3));
    *(uint4*)(vt + ((size_t)h * 64 + d) * S_LEN + dst) = P.qv;
  }
  {  // gates[s][hq][e]
    int s = id >> 4, hq = id & 15;
    const float4* qp = (const float4*)(q + ((size_t)s * HQ + hq) * DH);
    const float4* w0 = (const float4*)(wg);
    const float4* w1 = (const float4*)(wg + DH);
    const float4* w2 = (const float4*)(wg + 2 * DH);
    float g0 = 0.f, g1 = 0.f, g2 = 0.f;
    #pragma unroll
    for (int i = 0; i < 16; ++i) {
      float4 a = qp[i];
      float4 b0 = w0[i], b1 = w1[i], b2 = w2[i];
      g0 += a.x*b0.x + a.y*b0.y + a.z*b0.z + a.w*b0.w;
      g1 += a.x*b1.x + a.y*b1.y + a.z*b1.z + a.w*b1.w;
      g2 += a.x*b2.x + a.y*b2.y + a.z*b2.z + a.w*b2.w;
    }
    float* gp = gates + ((size_t)s * HQ + hq) * 3;
    gp[0] = g0; gp[1] = g1; gp[2] = g2;
  }
}

// ---- Stage B v3: wave-per-query compressed attn + pooling + exact top-8 ----
__global__ __launch_bounds__(256) void nsa_cmp_kernel(
    const float* __restrict__ q, const float* __restrict__ ck,
    const float* __restrict__ cv, const float* __restrict__ gates,
    float* __restrict__ out, int* __restrict__ sel) {
  int h  = blockIdx.x >> 9;          // / 512
  int s0 = (blockIdx.x & 511) << 2;  // * 4 queries, one per wave
  int tid = threadIdx.x;
  int w = tid >> 6, l = tid & 63;
  __shared__ float t4s[SC * DH];       // K (swizzled), then V (plain)
  __shared__ float pbuf[4][GQ][136];
  __shared__ float pkvb[4][128];
  float4* t4 = (float4*)t4s;

  int s  = s0 + w;
  int hq = l >> 3, cg = l & 7;

  {
    const float4* ck4 = (const float4*)(ck + (size_t)h * SC * DH);
    for (int f = tid; f < SC * 16; f += 256) {
      int c = f >> 4, i = f & 15;
      t4[(c << 4) | (i ^ (c & 7))] = ck4[f];
    }
  }
  float4 q4[16];
  {
    const float4* qp = (const float4*)(q + ((size_t)s * HQ + h * GQ + hq) * DH);
    #pragma unroll
    for (int i = 0; i < 16; ++i) q4[i] = qp[i];
  }
  __syncthreads();

  int nc = (s >= LCC - 1) ? ((s - (LCC - 1)) >> 4) + 1 : 0;

  float p[16];
  float m = -INFINITY;
  #pragma unroll
  for (int t = 0; t < 16; ++t) {
    int c = cg + (t << 3);
    float d = 0.f;
    #pragma unroll
    for (int i = 0; i < 16; ++i) {
      float4 kk = t4[(c << 4) | (i ^ cg)];
      d = fmaf(kk.x, q4[i].x, d); d = fmaf(kk.y, q4[i].y, d);
      d = fmaf(kk.z, q4[i].z, d); d = fmaf(kk.w, q4[i].w, d);
    }
    float x = (c < nc) ? d * SCALE : -INFINITY;
    p[t] = x;
    m = fmaxf(m, x);
  }
  m = fmaxf(m, __shfl_xor(m, 1));
  m = fmaxf(m, __shfl_xor(m, 2));
  m = fmaxf(m, __shfl_xor(m, 4));
  m = fmaxf(m, -1e30f);
  float ssum = 0.f;
  #pragma unroll
  for (int t = 0; t < 16; ++t) { p[t] = expf(p[t] - m); ssum += p[t]; }
  ssum += __shfl_xor(ssum, 1);
  ssum += __shfl_xor(ssum, 2);
  ssum += __shfl_xor(ssum, 4);
  float inv = 1.f / fmaxf(ssum, 1e-20f);
  #pragma unroll
  for (int t = 0; t < 16; ++t) {
    p[t] *= inv;
    pbuf[w][hq][cg + (t << 3)] = p[t];
  }
  #pragma unroll
  for (int t = 0; t < 16; ++t) {
    float v0 = p[t];
    v0 += __shfl_xor(v0, 8);
    v0 += __shfl_xor(v0, 16);
    v0 += __shfl_xor(v0, 32);
    p[t] = v0;
  }
  if (hq == 0) {
    #pragma unroll
    for (int t = 0; t < 16; ++t) pkvb[w][cg + (t << 3)] = p[t];
  }
  if (l < 32) {
    float pv;
    if (l < NOUT) {
      float tt = 0.f;
      #pragma unroll
      for (int u = 0; u < 5; ++u) tt += pkvb[w][l * 4 + u];
      pv = tt * 0.2f;
    } else pv = -1.0f;
    if (l == (s >> 6)) pv = INFINITY;
    int* dst = sel + ((size_t)h * S_LEN + s) * KSEL;
    #pragma unroll
    for (int kk = 0; kk < KSEL; ++kk) {
      float v0 = pv; int i0 = l;
      #pragma unroll
      for (int off = 16; off; off >>= 1) {
        float v1 = __shfl_xor(v0, off, 32);
        int   i1 = __shfl_xor(i0, off, 32);
        if (v1 > v0 || (v1 == v0 && i1 < i0)) { v0 = v1; i0 = i1; }
      }
      if (l == 0) dst[kk] = i0;
      if (l == i0) pv = -INFINITY;
    }
  }
  __syncthreads();
  {
    const float4* cv4 = (const float4*)(cv + (size_t)h * SC * DH);
    for (int f = tid; f < SC * 16; f += 256) t4[f] = cv4[f];
  }
  __syncthreads();
  {
    int d4 = l & 15, hg2 = l >> 4;
    float4 a0 = {0.f,0.f,0.f,0.f}, a1 = {0.f,0.f,0.f,0.f};
    #pragma unroll 2
    for (int c = 0; c < nc; ++c) {
      float4 vv = t4[(c << 4) | d4];
      float p0 = pbuf[w][hg2][c];
      float p1 = pbuf[w][hg2 + 4][c];
      a0.x = fmaf(p0, vv.x, a0.x); a0.y = fmaf(p0, vv.y, a0.y);
      a0.z = fmaf(p0, vv.z, a0.z); a0.w = fmaf(p0, vv.w, a0.w);
      a1.x = fmaf(p1, vv.x, a1.x); a1.y = fmaf(p1, vv.y, a1.y);
      a1.z = fmaf(p1, vv.z, a1.z); a1.w = fmaf(p1, vv.w, a1.w);
    }
    float g0 = gates[((size_t)s * HQ + h * GQ + hg2) * 3 + 2];
    float g1 = gates[((size_t)s * HQ + h * GQ + hg2 + 4) * 3 + 2];
    float4 o0, o1;
    o0.x = g0*a0.x; o0.y = g0*a0.y; o0.z = g0*a0.z; o0.w = g0*a0.w;
    o1.x = g1*a1.x; o1.y = g1*a1.y; o1.z = g1*a1.z; o1.w = g1*a1.w;
    ((float4*)(out + ((size_t)s * HQ + h * GQ + hg2) * DH))[d4] = o0;
    ((float4*)(out + ((size_t)s * HQ + h * GQ + hg2 + 4) * DH))[d4] = o1;
  }
}

// ---------------- selswa v2: split passes, MFMA bf16, DMA-staged ----------------
__device__ __forceinline__ void stage_chunk(const u16* kbh, const u16* vth,
                                            int cb, int w, int l,
                                            short* kT, short* vT) {
  #pragma unroll
  for (int r = 0; r < 2; ++r) {
    int seg = w * 2 + r;
    gl_lds16((const char*)kbh + (size_t)cb * 128 + seg * 1024 + l * 16,
             (char*)kT + seg * 1024);
    int drow = seg * 8 + (l >> 3);
    gl_lds16((const char*)vth + (size_t)drow * (S_LEN * 2) + cb * 2 + (l & 7) * 16,
             (char*)vT + seg * 1024);
  }
}

template <bool MASKED>
__device__ __forceinline__ void compute_chunk(
    const short* kT, const short* vT, short* pTw,
    int cb, int lo_l, u32 span, float selbias, int l,
    const bf16x8 (&qf)[2], f32x4 (&o)[4], float& mrun, float& lsum) {
  int col = l & 15;
  int lg8 = (l >> 4) << 3;
  int kq  = (l >> 4) << 2;
  int xr  = (l & 7) << 3;

  // ---- S^T = K · Q^T (Q pre-scaled by 2^-3) ----
  f32x4 st[4];
  #pragma unroll
  for (int mt = 0; mt < 4; ++mt) st[mt] = (f32x4){0.f, 0.f, 0.f, 0.f};
  __builtin_amdgcn_s_setprio(1);
  #pragma unroll
  for (int ks = 0; ks < 2; ++ks) {
    int co = (ks * 32 + lg8) ^ xr;
    #pragma unroll
    for (int mt = 0; mt < 4; ++mt) {
      bf16x8 kf = *(const bf16x8*)(&kT[((mt * 16 + col) << 6) | co]);
      st[mt] = __builtin_amdgcn_mfma_f32_16x16x32_bf16(kf, qf[ks], st[mt], 0, 0, 0);
    }
  }
  __builtin_amdgcn_s_setprio(0);

  // ---- mask ----
  float mc = -INFINITY;
  #pragma unroll
  for (int mt = 0; mt < 4; ++mt) {
    #pragma unroll
    for (int r = 0; r < 4; ++r) {
      float x = st[mt][r] + selbias;
      if (MASKED) {
        int key = cb + mt * 16 + kq + r;
        bool vis = (u32)(key - lo_l) <= span;
        x = vis ? x : -INFINITY;
      }
      st[mt][r] = x;
      mc = fmaxf(mc, x);
    }
  }
  mc = fmaxf(mc, __shfl_xor(mc, 16));
  mc = fmaxf(mc, __shfl_xor(mc, 32));

  // ---- defer-max online softmax (T13, THR=8) ----
  if (!__all(mc <= mrun + 8.f)) {
    float mn = fmaxf(fmaxf(mrun, mc), -1e30f);
    float fr = __expf(mrun - mn);
    #pragma unroll
    for (int mt = 0; mt < 4; ++mt) o[mt] *= fr;
    lsum *= fr;
    mrun = mn;
  }
  float ps = 0.f;
  #pragma unroll
  for (int mt = 0; mt < 4; ++mt) {
    #pragma unroll
    for (int r = 0; r < 4; ++r) {
      float p = __expf(st[mt][r] - mrun);
      st[mt][r] = p; ps += p;
    }
  }
  ps += __shfl_xor(ps, 16);
  ps += __shfl_xor(ps, 32);
  lsum += ps;

  // ---- P -> bf16 (cvt_pk) -> per-wave LDS ----
  int pc = col << 6;
  #pragma unroll
  for (int mt = 0; mt < 4; ++mt) {
    #pragma unroll
    for (int pr = 0; pr < 2; ++pr) {
      u32 pk;
      asm("v_cvt_pk_bf16_f32 %0, %1, %2"
          : "=v"(pk) : "v"(st[mt][pr * 2]), "v"(st[mt][pr * 2 + 1]));
      int key = mt * 16 + kq + pr * 2;
      *(u32*)(&pTw[pc | (key ^ xr)]) = pk;
    }
  }

  // ---- O^T += V^T · P ----
  __builtin_amdgcn_s_setprio(1);
  #pragma unroll
  for (int ks = 0; ks < 2; ++ks) {
    int co = (ks * 32 + lg8) ^ xr;
    bf16x8 pf = *(const bf16x8*)(&pTw[pc | co]);
    #pragma unroll
    for (int mt = 0; mt < 4; ++mt) {
      bf16x8 vf = *(const bf16x8*)(&vT[((mt * 16 + col) << 6) | co]);
      o[mt] = __builtin_amdgcn_mfma_f32_16x16x32_bf16(vf, pf, o[mt], 0, 0, 0);
    }
  }
  __builtin_amdgcn_s_setprio(0);
}

// mode: 0 = SEL only (RMW out), 1 = SWA only (RMW out), 2 = combined grid
//       (first half SEL '='->osel, second half SWA RMW out; merge adds osel)
__global__ __launch_bounds__(256) void nsa_selswa_kernel(
    const float* __restrict__ q, const u16* __restrict__ kb,
    const u16* __restrict__ vt, const float* __restrict__ gates,
    const int* __restrict__ sel, float* __restrict__ out,
    float* __restrict__ osel, int mode) {
  int bid = blockIdx.x;
  int pass, rest;
  if (mode == 2) { pass = bid >= HKV * 256; rest = bid & (HKV * 256 - 1); }
  else           { pass = mode; rest = bid; }
  int h  = rest >> 8;
  int s0 = (rest & 255) * QTS;
  int b0 = s0 >> 6;
  int tid = threadIdx.x;
  int w = tid >> 6, l = tid & 63;
  __shared__ __align__(16) short kTb[2][64 * 64];
  __shared__ __align__(16) short vTb[2][64 * 64];
  __shared__ __align__(16) short pT[4][16 * 64];   // selsh aliased below
  int* selsh = (int*)&pT[0][0];

  if (tid < 64)
    selsh[tid] = sel[((size_t)h * S_LEN + s0 + (tid >> 3)) * KSEL + (tid & 7)];

  int col = l & 15, qq = col & 7, gh2 = col >> 3;
  int s_lane = s0 + qq;
  size_t qrow = (size_t)s_lane * HQ + h * 8 + w * 2 + gh2;

  bf16x8 qf[2];   // Q pre-scaled by SCALE (exact 2^-3)
  #pragma unroll
  for (int ks = 0; ks < 2; ++ks) {
    const float4* gp = (const float4*)(q + qrow * DH + ks * 32 + ((l >> 4) << 3));
    float4 a = gp[0], b = gp[1];
    union { bf16x8 v; u16 u[8]; } P;
    P.u[0]=f2bf(a.x*SCALE); P.u[1]=f2bf(a.y*SCALE); P.u[2]=f2bf(a.z*SCALE); P.u[3]=f2bf(a.w*SCALE);
    P.u[4]=f2bf(b.x*SCALE); P.u[5]=f2bf(b.y*SCALE); P.u[6]=f2bf(b.z*SCALE); P.u[7]=f2bf(b.w*SCALE);
    qf[ks] = P.v;
  }
  float gate = gates[qrow * 3 + (pass ? 1 : 0)];
  __syncthreads();

  u32 qmask = 0;
  #pragma unroll
  for (int j = 0; j < 8; ++j) qmask |= 1u << selsh[qq * 8 + j];

  const u16* kbh = kb + (size_t)h * S_LEN * 64;
  const u16* vth = vt + (size_t)h * 64 * S_LEN;
  short* pTw = pT[w];

  f32x4 o[4];
  #pragma unroll
  for (int mt = 0; mt < 4; ++mt) o[mt] = (f32x4){0.f, 0.f, 0.f, 0.f};
  float mrun = -INFINITY, lsum = 0.f;

  if (pass == 0) {
    // ---- SEL: union of selected causal blocks ----
    u32 un = qmask;
    un |= (u32)__shfl_xor((int)un, 1);
    un |= (u32)__shfl_xor((int)un, 2);
    un |= (u32)__shfl_xor((int)un, 4);
    un &= (2u << b0) - 1;              // drop phantom blocks beyond causal
    u32 rem = un;
    int cb = __builtin_ctz(rem) << 6;
    int par = 0;
    stage_chunk(kbh, vth, cb, w, l, kTb[0], vTb[0]);
    __syncthreads();
    while (1) {
      u32 rem2 = rem & (rem - 1);
      int cbn = rem2 ? (__builtin_ctz(rem2) << 6) : -1;
      if (cbn >= 0) stage_chunk(kbh, vth, cbn, w, l, kTb[par ^ 1], vTb[par ^ 1]);
      float selbias = ((qmask >> (cb >> 6)) & 1) ? 0.f : -INFINITY;
      if (cb == b0 * 64)
        compute_chunk<true>(kTb[par], vTb[par], pTw, cb, 0, (u32)s_lane,
                            selbias, l, qf, o, mrun, lsum);
      else
        compute_chunk<false>(kTb[par], vTb[par], pTw, cb, 0, 0,
                             selbias, l, qf, o, mrun, lsum);
      __syncthreads();
      if (cbn < 0) break;
      rem = rem2; cb = cbn; par ^= 1;
    }
  } else {
    // ---- SWA ----
    int t0 = s0 - (WIN - 1); if (t0 < 0) t0 = 0;
    int lo_l = s_lane - (WIN - 1);
    int cb = t0 & ~63;
    int cbt = b0 * 64;
    int par = 0;
    stage_chunk(kbh, vth, cb, w, l, kTb[0], vTb[0]);
    __syncthreads();
    while (1) {
      int cbn = (cb < cbt) ? cb + 64 : -1;
      if (cbn >= 0) stage_chunk(kbh, vth, cbn, w, l, kTb[par ^ 1], vTb[par ^ 1]);
      if ((cb + 504 < s0) || (cb == cbt))
        compute_chunk<true>(kTb[par], vTb[par], pTw, cb, lo_l, (u32)(WIN - 1),
                            0.f, l, qf, o, mrun, lsum);
      else
        compute_chunk<false>(kTb[par], vTb[par], pTw, cb, 0, 0,
                             0.f, l, qf, o, mrun, lsum);
      __syncthreads();
      if (cbn < 0) break;
      cb = cbn; par ^= 1;
    }
  }

  float gv = gate / fmaxf(lsum, 1e-20f);
  int kq = (l >> 4) << 2;
  if (mode == 2 && pass == 0) {
    #pragma unroll
    for (int mt = 0; mt < 4; ++mt) {
      float4 pv;
      pv.x = gv * o[mt][0]; pv.y = gv * o[mt][1];
      pv.z = gv * o[mt][2]; pv.w = gv * o[mt][3];
      *(float4*)(osel + qrow * DH + mt * 16 + kq) = pv;
    }
  } else {
    #pragma unroll
    for (int mt = 0; mt < 4; ++mt) {
      float4* op = (float4*)(out + qrow * DH + mt * 16 + kq);
      float4 pv = *op;
      pv.x = fmaf(gv, o[mt][0], pv.x); pv.y = fmaf(gv, o[mt][1], pv.y);
      pv.z = fmaf(gv, o[mt][2], pv.z); pv.w = fmaf(gv, o[mt][3], pv.w);
      *op = pv;
    }
  }
}

__global__ __launch_bounds__(256) void nsa_merge_kernel(
    const float* __restrict__ osel, float* __restrict__ out) {
  int i = blockIdx.x * 256 + threadIdx.x;
  float4 a = ((const float4*)osel)[i];
  float4 b = ((float4*)out)[i];
  b.x += a.x; b.y += a.y; b.z += a.z; b.w += a.w;
  ((float4*)out)[i] = b;
}

extern "C" void kernel_launch(void* const* d_in, const int* in_sizes, int n_in,
                              void* d_out, int out_size, void* d_ws, size_t ws_size,
                              hipStream_t stream) {
  const float* q  = (const float*)d_in[0];
  const float* k  = (const float*)d_in[1];
  const float* v  = (const float*)d_in[2];
  const float* wk = (const float*)d_in[3];
  const float* wv = (const float*)d_in[4];
  const float* wg = (const float*)d_in[5];
  float* out = (float*)d_out;

  float* ck    = (float*)d_ws;                               // 16256 f
  float* cv    = ck + (size_t)HKV * SC * DH;                 // 16256 f
  float* gates = cv + (size_t)HKV * SC * DH;                 // 98304 f
  int*   sel   = (int*)(gates + (size_t)S_LEN * HQ * 3);     // 32768 i
  u16*   kb    = (u16*)(sel + (size_t)HKV * S_LEN * KSEL);   // 262144 u16
  u16*   vt    = kb + (size_t)HKV * S_LEN * DH;              // 262144 u16
  float* osel  = (float*)(vt + (size_t)HKV * DH * S_LEN);    // 2097152 f
  size_t need  = (size_t)((char*)(osel + (size_t)S_LEN * HQ * DH) - (char*)d_ws);

  nsa_conv_kernel<<<HKV * SC, 256, 0, stream>>>(k, v, wk, wv, ck, cv);
  nsa_prep_kernel<<<128, 256, 0, stream>>>(q, k, v, wg, kb, vt, gates);
  nsa_cmp_kernel<<<HKV * (S_LEN / 4), 256, 0, stream>>>(q, ck, cv, gates, out, sel);
  if (ws_size >= need) {
    nsa_selswa_kernel<<<2 * HKV * 256, 256, 0, stream>>>(q, kb, vt, gates, sel, out, osel, 2);
    nsa_merge_kernel<<<(S_LEN * HQ * DH / 4) / 256, 256, 0, stream>>>(osel, out);
  } else {
    nsa_selswa_kernel<<<HKV * 256, 256, 0, stream>>>(q, kb, vt, gates, sel, out, osel, 0);
    nsa_selswa_kernel<<<HKV * 256, 256, 0, stream>>>(q, kb, vt, gates, sel, out, osel, 1);
  }
}